// Round 1
// baseline (1039.485 us; speedup 1.0000x reference)
//
#include <hip/hip_runtime.h>
#include <hip/hip_bf16.h>

#define NN 50000
#define EE 600000
#define FH 128
#define GG 128
#define CC 16

// ---- degree accumulation: deg[dst] += ew ----
__global__ __launch_bounds__(256) void k_deg(const int* __restrict__ dst,
                                             const float* __restrict__ ew,
                                             float* __restrict__ deg) {
    for (int e = blockIdx.x * 256 + threadIdx.x; e < EE; e += gridDim.x * 256)
        unsafeAtomicAdd(&deg[dst[e]], ew[e]);
}

// ---- dinv = rsqrt(deg + 1) in place ----
__global__ __launch_bounds__(256) void k_dinv(float* __restrict__ deg) {
    int n = blockIdx.x * 256 + threadIdx.x;
    if (n < NN) deg[n] = rsqrtf(deg[n] + 1.0f);
}

// ---- Y[nrows,128] = X[nrows,128] @ W[128,128], fp32 ----
// W in LDS row-major (64KB, conflict-free: 2 lanes/bank). 32-row x tile
// transposed in LDS (pitch 36 -> 16B-aligned broadcast reads). Each wave
// owns 8 rows, each lane cols {lane, lane+64}: 16 FMA per k per lane.
__global__ __launch_bounds__(256, 1) void k_gemm128(const float* __restrict__ X,
                                                    const float* __restrict__ W,
                                                    float* __restrict__ Y,
                                                    int nrows) {
    __shared__ float Wl[128 * 128];
    __shared__ float xT[128][36];
    const int tid = threadIdx.x;
    for (int i = tid; i < 128 * 128 / 4; i += 256)
        ((float4*)Wl)[i] = ((const float4*)W)[i];
    const int wave = tid >> 6, lane = tid & 63, rb = wave * 8;
    const int ntiles = (nrows + 31) / 32;
    for (int tile = blockIdx.x; tile < ntiles; tile += gridDim.x) {
        const int r0 = tile * 32;
        __syncthreads();  // protect xT (and W on iter 0) before overwrite
        for (int i = tid; i < 1024; i += 256) {
            int r = i >> 5, c4 = i & 31;
            float4 v = make_float4(0.f, 0.f, 0.f, 0.f);
            if (r0 + r < nrows) v = ((const float4*)(X + (size_t)(r0 + r) * 128))[c4];
            xT[c4 * 4 + 0][r] = v.x; xT[c4 * 4 + 1][r] = v.y;
            xT[c4 * 4 + 2][r] = v.z; xT[c4 * 4 + 3][r] = v.w;
        }
        __syncthreads();
        float acc[8][2];
#pragma unroll
        for (int r = 0; r < 8; r++) { acc[r][0] = 0.f; acc[r][1] = 0.f; }
#pragma unroll 4
        for (int k = 0; k < 128; k++) {
            float w0 = Wl[k * 128 + lane];
            float w1 = Wl[k * 128 + 64 + lane];
#pragma unroll
            for (int r = 0; r < 8; r++) {
                float xv = xT[k][rb + r];
                acc[r][0] = fmaf(xv, w0, acc[r][0]);
                acc[r][1] = fmaf(xv, w1, acc[r][1]);
            }
        }
#pragma unroll
        for (int r = 0; r < 8; r++) {
            int row = r0 + rb + r;
            if (row < nrows) {
                Y[(size_t)row * 128 + lane] = acc[r][0];
                Y[(size_t)row * 128 + 64 + lane] = acc[r][1];
            }
        }
    }
}

// ---- edge scatter: AGG[dst] += XW[src] * (dinv[src]*ew*dinv[dst]) ----
// 128 threads per edge (one feature each), 2 edges per 256-thread block.
__global__ __launch_bounds__(256) void k_scatter(const int* __restrict__ src,
                                                 const int* __restrict__ dst,
                                                 const float* __restrict__ ew,
                                                 const float* __restrict__ dinv,
                                                 const float* __restrict__ XW,
                                                 float* __restrict__ AGG) {
    const int half = threadIdx.x >> 7;
    const int f = threadIdx.x & 127;
    for (int e = blockIdx.x * 2 + half; e < EE; e += gridDim.x * 2) {
        int s = src[e], d = dst[e];
        float nm = dinv[s] * ew[e] * dinv[d];
        float v = XW[(size_t)s * 128 + f] * nm;
        unsafeAtomicAdd(&AGG[(size_t)d * 128 + f], v);
    }
}

// ---- finalize: H = relu(AGG + XW*dinv^2 + b), in place on AGG ----
__global__ __launch_bounds__(256) void k_finalize(float* __restrict__ AGG,
                                                  const float* __restrict__ XW,
                                                  const float* __restrict__ dinv,
                                                  const float* __restrict__ b) {
    size_t idx = (size_t)blockIdx.x * 256 + threadIdx.x;
    if (idx < (size_t)NN * 128) {
        int n = (int)(idx >> 7), f = (int)(idx & 127);
        float di = dinv[n];
        float v = AGG[idx] + XW[idx] * di * di + b[f];
        AGG[idx] = fmaxf(v, 0.0f);
    }
}

// ---- pooling: per-graph max / sum / count ----
// h >= 0 (post-ReLU) so uint-bitpattern atomicMax == float max; init 0.
__global__ __launch_bounds__(256) void k_pool(const float* __restrict__ H,
                                              const int* __restrict__ batch,
                                              float* __restrict__ MX,
                                              float* __restrict__ SM,
                                              float* __restrict__ CNT) {
    size_t idx = (size_t)blockIdx.x * 256 + threadIdx.x;
    if (idx < (size_t)NN * 128) {
        int n = (int)(idx >> 7), f = (int)(idx & 127);
        int g = batch[n];
        float v = H[idx];
        atomicMax((unsigned int*)&MX[(size_t)g * 128 + f], __float_as_uint(v));
        unsafeAtomicAdd(&SM[(size_t)g * 128 + f], v);
        if (f == 0) unsafeAtomicAdd(&CNT[g], 1.0f);
    }
}

// ---- head: z = [max, mean] @ linW + linb, log_softmax over 16 classes ----
__global__ __launch_bounds__(64) void k_final(const float* __restrict__ MX,
                                              const float* __restrict__ SM,
                                              const float* __restrict__ CNT,
                                              const float* __restrict__ linW,
                                              const float* __restrict__ linb,
                                              float* __restrict__ out) {
    int g = blockIdx.x, lane = threadIdx.x;
    if (lane < CC) {
        float rc = 1.0f / fmaxf(CNT[g], 1.0f);
        float z = linb[lane];
        for (int f = 0; f < 128; f++) {
            z = fmaf(MX[(size_t)g * 128 + f], linW[f * CC + lane], z);
            z = fmaf(SM[(size_t)g * 128 + f] * rc, linW[(128 + f) * CC + lane], z);
        }
        float m = z;
        for (int o = 8; o >= 1; o >>= 1) m = fmaxf(m, __shfl_xor(m, o, 16));
        float ex = expf(z - m), s = ex;
        for (int o = 8; o >= 1; o >>= 1) s += __shfl_xor(s, o, 16);
        out[g * CC + lane] = z - m - logf(s);
    }
}

extern "C" void kernel_launch(void* const* d_in, const int* in_sizes, int n_in,
                              void* d_out, int out_size, void* d_ws, size_t ws_size,
                              hipStream_t stream) {
    const float* x    = (const float*)d_in[0];
    const int*   ei   = (const int*)d_in[1];
    const float* ew   = (const float*)d_in[2];
    const int*   batch= (const int*)d_in[3];
    const float* W1   = (const float*)d_in[4];
    const float* b1   = (const float*)d_in[5];
    const float* W2   = (const float*)d_in[6];
    const float* b2   = (const float*)d_in[7];
    const float* linW = (const float*)d_in[8];
    const float* linb = (const float*)d_in[9];
    float* out = (float*)d_out;

    float* A    = (float*)d_ws;                 // xw buffer  [N,128]
    float* B    = A + (size_t)NN * 128;         // agg/h      [N,128]
    float* DEG  = B + (size_t)NN * 128;         // deg -> dinv [N]
    float* MAXB = DEG + NN;                     // [G,128]
    float* SUMB = MAXB + (size_t)GG * 128;      // [G,128]
    float* CNT  = SUMB + (size_t)GG * 128;      // [G]

    const int* src = ei;        // edge_index row 0
    const int* dst = ei + EE;   // edge_index row 1

    // degree -> dinv (shared by both layers)
    hipMemsetAsync(DEG, 0, NN * sizeof(float), stream);
    k_deg<<<2048, 256, 0, stream>>>(dst, ew, DEG);
    k_dinv<<<(NN + 255) / 256, 256, 0, stream>>>(DEG);

    // layer 1
    k_gemm128<<<1563, 256, 0, stream>>>(x, W1, A, NN);
    hipMemsetAsync(B, 0, (size_t)NN * 128 * sizeof(float), stream);
    k_scatter<<<2048, 256, 0, stream>>>(src, dst, ew, DEG, A, B);
    k_finalize<<<25000, 256, 0, stream>>>(B, A, DEG, b1);   // h1 in B

    // layer 2
    k_gemm128<<<1563, 256, 0, stream>>>(B, W2, A, NN);      // xw2 in A
    hipMemsetAsync(B, 0, (size_t)NN * 128 * sizeof(float), stream);
    k_scatter<<<2048, 256, 0, stream>>>(src, dst, ew, DEG, A, B);
    k_finalize<<<25000, 256, 0, stream>>>(B, A, DEG, b2);   // h2 in B

    // pooling + head
    hipMemsetAsync(MAXB, 0, (size_t)(GG * 128 * 2 + GG) * sizeof(float), stream);
    k_pool<<<25000, 256, 0, stream>>>(B, batch, MAXB, SUMB, CNT);
    k_final<<<GG, 64, 0, stream>>>(MAXB, SUMB, CNT, linW, linb, out);
}

// Round 2
// 520.194 us; speedup vs baseline: 1.9983x; 1.9983x over previous
//
#include <hip/hip_runtime.h>
#include <hip/hip_bf16.h>

#define NN 50000
#define EE 600000
#define FH 128
#define GG 128
#define CC 16

// ---- degree (weighted, float) + in-degree (int) histogram over dst ----
__global__ __launch_bounds__(256) void k_deg(const int* __restrict__ dst,
                                             const float* __restrict__ ew,
                                             float* __restrict__ deg,
                                             int* __restrict__ cur) {
    for (int e = blockIdx.x * 256 + threadIdx.x; e < EE; e += gridDim.x * 256) {
        int d = dst[e];
        unsafeAtomicAdd(&deg[d], ew[e]);
        atomicAdd(&cur[d], 1);
    }
}

// ---- dinv = rsqrt(deg + 1) in place ----
__global__ __launch_bounds__(256) void k_dinv(float* __restrict__ deg) {
    int n = blockIdx.x * 256 + threadIdx.x;
    if (n < NN) deg[n] = rsqrtf(deg[n] + 1.0f);
}

// ---- single-block exclusive scan of cur[] (in-degree) -> rowptr, cursor ----
// cur[i] is rewritten in place to the running start offset (the bin cursor).
__global__ __launch_bounds__(1024) void k_scan(int* __restrict__ cur,
                                               int* __restrict__ rowptr) {
    __shared__ int psum[1024];
    const int tid = threadIdx.x;
    const int CH = (NN + 1023) / 1024;  // 49
    const int s0 = tid * CH, s1 = min(s0 + CH, NN);
    int local = 0;
    for (int i = s0; i < s1; i++) local += cur[i];
    psum[tid] = local;
    __syncthreads();
    for (int off = 1; off < 1024; off <<= 1) {
        int add = (tid >= off) ? psum[tid - off] : 0;
        __syncthreads();
        psum[tid] += add;
        __syncthreads();
    }
    int run = psum[tid] - local;  // exclusive prefix of this chunk
    for (int i = s0; i < s1; i++) {
        int c = cur[i];
        rowptr[i] = run;
        cur[i] = run;
        run += c;
    }
    if (tid == 1023) rowptr[NN] = psum[1023];
}

// ---- fill CSR buckets with (src, norm) pairs ----
__global__ __launch_bounds__(256) void k_binfill(const int* __restrict__ src,
                                                 const int* __restrict__ dst,
                                                 const float* __restrict__ ew,
                                                 const float* __restrict__ dinv,
                                                 int* __restrict__ cur,
                                                 int2* __restrict__ bucket) {
    for (int e = blockIdx.x * 256 + threadIdx.x; e < EE; e += gridDim.x * 256) {
        int s = src[e], d = dst[e];
        float nm = dinv[s] * ew[e] * dinv[d];
        int pos = atomicAdd(&cur[d], 1);
        bucket[pos] = make_int2(s, __float_as_int(nm));
    }
}

// ---- graph start offsets: gstart[g] = lower_bound(batch, g) ----
__global__ __launch_bounds__(256) void k_gstart(const int* __restrict__ batch,
                                                int* __restrict__ gstart) {
    int g = threadIdx.x;
    if (g > GG) return;
    int lo = 0, hi = NN;
    while (lo < hi) {
        int mid = (lo + hi) >> 1;
        if (batch[mid] < g) lo = mid + 1; else hi = mid;
    }
    gstart[g] = lo;
}

// ---- Y[nrows,128] = X[nrows,128] @ W[128,128], fp32 ----
__global__ __launch_bounds__(256, 1) void k_gemm128(const float* __restrict__ X,
                                                    const float* __restrict__ W,
                                                    float* __restrict__ Y,
                                                    int nrows) {
    __shared__ float Wl[128 * 128];
    __shared__ float xT[128][36];
    const int tid = threadIdx.x;
    for (int i = tid; i < 128 * 128 / 4; i += 256)
        ((float4*)Wl)[i] = ((const float4*)W)[i];
    const int wave = tid >> 6, lane = tid & 63, rb = wave * 8;
    const int ntiles = (nrows + 31) / 32;
    for (int tile = blockIdx.x; tile < ntiles; tile += gridDim.x) {
        const int r0 = tile * 32;
        __syncthreads();
        for (int i = tid; i < 1024; i += 256) {
            int r = i >> 5, c4 = i & 31;
            float4 v = make_float4(0.f, 0.f, 0.f, 0.f);
            if (r0 + r < nrows) v = ((const float4*)(X + (size_t)(r0 + r) * 128))[c4];
            xT[c4 * 4 + 0][r] = v.x; xT[c4 * 4 + 1][r] = v.y;
            xT[c4 * 4 + 2][r] = v.z; xT[c4 * 4 + 3][r] = v.w;
        }
        __syncthreads();
        float acc[8][2];
#pragma unroll
        for (int r = 0; r < 8; r++) { acc[r][0] = 0.f; acc[r][1] = 0.f; }
#pragma unroll 4
        for (int k = 0; k < 128; k++) {
            float w0 = Wl[k * 128 + lane];
            float w1 = Wl[k * 128 + 64 + lane];
#pragma unroll
            for (int r = 0; r < 8; r++) {
                float xv = xT[k][rb + r];
                acc[r][0] = fmaf(xv, w0, acc[r][0]);
                acc[r][1] = fmaf(xv, w1, acc[r][1]);
            }
        }
#pragma unroll
        for (int r = 0; r < 8; r++) {
            int row = r0 + rb + r;
            if (row < nrows) {
                Y[(size_t)row * 128 + lane] = acc[r][0];
                Y[(size_t)row * 128 + 64 + lane] = acc[r][1];
            }
        }
    }
}

// ---- gather-aggregate + self-loop + bias + relu, one wave per node ----
__global__ __launch_bounds__(256) void k_gather(const float* __restrict__ XW,
                                                const int* __restrict__ rowptr,
                                                const int2* __restrict__ bucket,
                                                const float* __restrict__ dinv,
                                                const float* __restrict__ b,
                                                float* __restrict__ H) {
    const int wave = threadIdx.x >> 6, lane = threadIdx.x & 63;
    const int n = blockIdx.x * 4 + wave;
    if (n >= NN) return;
    const float di = dinv[n];
    const float sl = di * di;
    const float* xr = XW + (size_t)n * 128;
    float acc0 = xr[lane] * sl;
    float acc1 = xr[64 + lane] * sl;
    const int e1 = rowptr[n + 1];
    for (int e = rowptr[n]; e < e1; e++) {
        int2 p = bucket[e];
        float nm = __int_as_float(p.y);
        const float* r = XW + (size_t)p.x * 128;
        acc0 = fmaf(r[lane], nm, acc0);
        acc1 = fmaf(r[64 + lane], nm, acc1);
    }
    H[(size_t)n * 128 + lane]      = fmaxf(acc0 + b[lane], 0.f);
    H[(size_t)n * 128 + 64 + lane] = fmaxf(acc1 + b[64 + lane], 0.f);
}

// ---- pooling over sorted batch ranges: 8 node-slices per graph ----
__global__ __launch_bounds__(128) void k_pool2(const float* __restrict__ H,
                                               const int* __restrict__ gstart,
                                               float* __restrict__ MX,
                                               float* __restrict__ SM) {
    const int g = blockIdx.x >> 3, slice = blockIdx.x & 7;
    const int f = threadIdx.x;
    const int n0 = gstart[g], n1 = gstart[g + 1];
    float mx = 0.f, sm = 0.f;  // h >= 0 post-relu, so 0 is a valid max identity
    for (int n = n0 + slice; n < n1; n += 8) {
        float v = H[(size_t)n * 128 + f];
        mx = fmaxf(mx, v);
        sm += v;
    }
    atomicMax((unsigned int*)&MX[(size_t)g * 128 + f], __float_as_uint(mx));
    unsafeAtomicAdd(&SM[(size_t)g * 128 + f], sm);
}

// ---- head: z = [max, mean] @ linW + linb, log_softmax over 16 classes ----
__global__ __launch_bounds__(64) void k_final(const float* __restrict__ MX,
                                              const float* __restrict__ SM,
                                              const int* __restrict__ gstart,
                                              const float* __restrict__ linW,
                                              const float* __restrict__ linb,
                                              float* __restrict__ out) {
    int g = blockIdx.x, lane = threadIdx.x;
    if (lane < CC) {
        int cnt = gstart[g + 1] - gstart[g];
        float rc = 1.0f / fmaxf((float)cnt, 1.0f);
        float z = linb[lane];
        for (int f = 0; f < 128; f++) {
            z = fmaf(MX[(size_t)g * 128 + f], linW[f * CC + lane], z);
            z = fmaf(SM[(size_t)g * 128 + f] * rc, linW[(128 + f) * CC + lane], z);
        }
        float m = z;
        for (int o = 8; o >= 1; o >>= 1) m = fmaxf(m, __shfl_xor(m, o, 16));
        float ex = expf(z - m), s = ex;
        for (int o = 8; o >= 1; o >>= 1) s += __shfl_xor(s, o, 16);
        out[g * CC + lane] = z - m - logf(s);
    }
}

extern "C" void kernel_launch(void* const* d_in, const int* in_sizes, int n_in,
                              void* d_out, int out_size, void* d_ws, size_t ws_size,
                              hipStream_t stream) {
    const float* x    = (const float*)d_in[0];
    const int*   ei   = (const int*)d_in[1];
    const float* ew   = (const float*)d_in[2];
    const int*   batch= (const int*)d_in[3];
    const float* W1   = (const float*)d_in[4];
    const float* b1   = (const float*)d_in[5];
    const float* W2   = (const float*)d_in[6];
    const float* b2   = (const float*)d_in[7];
    const float* linW = (const float*)d_in[8];
    const float* linb = (const float*)d_in[9];
    float* out = (float*)d_out;

    // workspace layout (all 4B types; bucket int2 is 8B-aligned by construction)
    float* A      = (float*)d_ws;                  // [N,128] xw
    float* B      = A + (size_t)NN * 128;          // [N,128] h
    int2*  BUCKET = (int2*)(B + (size_t)NN * 128); // [E] (src, norm bits)
    float* DEG    = (float*)(BUCKET + EE);         // [N] deg -> dinv
    int*   ROWPTR = (int*)(DEG + NN);              // [N+1]
    int*   CUR    = ROWPTR + NN + 1;               // [N] histogram -> cursor
    int*   GSTART = CUR + NN;                      // [G+1]
    float* MAXB   = (float*)(GSTART + GG + 1);     // [G,128]
    float* SUMB   = MAXB + (size_t)GG * 128;       // [G,128]

    const int* src = ei;
    const int* dst = ei + EE;

    // zero the per-call accumulators
    hipMemsetAsync(DEG, 0, NN * sizeof(float), stream);
    hipMemsetAsync(CUR, 0, NN * sizeof(int), stream);
    hipMemsetAsync(MAXB, 0, (size_t)GG * 128 * 2 * sizeof(float), stream);

    // CSR build (shared by both layers)
    k_deg<<<1024, 256, 0, stream>>>(dst, ew, DEG, CUR);
    k_dinv<<<(NN + 255) / 256, 256, 0, stream>>>(DEG);
    k_scan<<<1, 1024, 0, stream>>>(CUR, ROWPTR);
    k_binfill<<<1024, 256, 0, stream>>>(src, dst, ew, DEG, CUR, BUCKET);
    k_gstart<<<1, 256, 0, stream>>>(batch, GSTART);

    // layer 1
    k_gemm128<<<1563, 256, 0, stream>>>(x, W1, A, NN);
    k_gather<<<(NN + 3) / 4, 256, 0, stream>>>(A, ROWPTR, BUCKET, DEG, b1, B);

    // layer 2
    k_gemm128<<<1563, 256, 0, stream>>>(B, W2, A, NN);
    k_gather<<<(NN + 3) / 4, 256, 0, stream>>>(A, ROWPTR, BUCKET, DEG, b2, B);

    // pooling + head
    k_pool2<<<GG * 8, 128, 0, stream>>>(B, GSTART, MAXB, SUMB);
    k_final<<<GG, 64, 0, stream>>>(MAXB, SUMB, GSTART, linW, linb, out);
}

// Round 3
// 420.502 us; speedup vs baseline: 2.4720x; 1.2371x over previous
//
#include <hip/hip_runtime.h>
#include <hip/hip_bf16.h>

#define NN 50000
#define EE 600000
#define FH 128
#define GG 128
#define CC 16
#define NBLK ((NN + 255) / 256)   // 196 scan blocks

// ---- degree (weighted, float) + in-degree (int) histogram over dst ----
__global__ __launch_bounds__(256) void k_deg(const int* __restrict__ dst,
                                             const float* __restrict__ ew,
                                             float* __restrict__ deg,
                                             int* __restrict__ cur) {
    for (int e = blockIdx.x * 256 + threadIdx.x; e < EE; e += gridDim.x * 256) {
        int d = dst[e];
        unsafeAtomicAdd(&deg[d], ew[e]);
        atomicAdd(&cur[d], 1);
    }
}

// ---- dinv = rsqrt(deg + 1) in place ----
__global__ __launch_bounds__(256) void k_dinv(float* __restrict__ deg) {
    int n = blockIdx.x * 256 + threadIdx.x;
    if (n < NN) deg[n] = rsqrtf(deg[n] + 1.0f);
}

// ---- multi-block exclusive scan of cur[] (3 phases) ----
__global__ __launch_bounds__(256) void k_scanA(const int* __restrict__ cur,
                                               int* __restrict__ bs) {
    int i = blockIdx.x * 256 + threadIdx.x;
    int v = (i < NN) ? cur[i] : 0;
#pragma unroll
    for (int o = 32; o >= 1; o >>= 1) v += __shfl_down(v, o, 64);
    __shared__ int ws[4];
    if ((threadIdx.x & 63) == 0) ws[threadIdx.x >> 6] = v;
    __syncthreads();
    if (threadIdx.x == 0) bs[blockIdx.x] = ws[0] + ws[1] + ws[2] + ws[3];
}

__global__ __launch_bounds__(256) void k_scanB(const int* __restrict__ bs,
                                               int* __restrict__ bo) {
    __shared__ int s[256];
    int t = threadIdx.x;
    int v = (t < NBLK) ? bs[t] : 0;
    s[t] = v;
    __syncthreads();
    for (int off = 1; off < 256; off <<= 1) {
        int add = (t >= off) ? s[t - off] : 0;
        __syncthreads();
        s[t] += add;
        __syncthreads();
    }
    if (t < NBLK) bo[t] = s[t] - v;  // exclusive block offset
}

__global__ __launch_bounds__(256) void k_scanC(const int* __restrict__ bo,
                                               int* __restrict__ rowptr,
                                               int* __restrict__ cur) {
    __shared__ int s[256];
    int t = threadIdx.x;
    int i = blockIdx.x * 256 + t;
    int v = (i < NN) ? cur[i] : 0;
    s[t] = v;
    __syncthreads();
    for (int off = 1; off < 256; off <<= 1) {
        int add = (t >= off) ? s[t - off] : 0;
        __syncthreads();
        s[t] += add;
        __syncthreads();
    }
    int excl = s[t] - v + bo[blockIdx.x];
    if (i < NN) { rowptr[i] = excl; cur[i] = excl; }
    if (i == 0) rowptr[NN] = EE;   // total in-degree is exactly E
}

// ---- fill CSR buckets with (src, norm) pairs ----
__global__ __launch_bounds__(256) void k_binfill(const int* __restrict__ src,
                                                 const int* __restrict__ dst,
                                                 const float* __restrict__ ew,
                                                 const float* __restrict__ dinv,
                                                 int* __restrict__ cur,
                                                 int2* __restrict__ bucket) {
    for (int e = blockIdx.x * 256 + threadIdx.x; e < EE; e += gridDim.x * 256) {
        int s = src[e], d = dst[e];
        float nm = dinv[s] * ew[e] * dinv[d];
        int pos = atomicAdd(&cur[d], 1);
        bucket[pos] = make_int2(s, __float_as_int(nm));
    }
}

// ---- graph start offsets: gstart[g] = lower_bound(batch, g) ----
__global__ __launch_bounds__(256) void k_gstart(const int* __restrict__ batch,
                                                int* __restrict__ gstart) {
    int g = threadIdx.x;
    if (g > GG) return;
    int lo = 0, hi = NN;
    while (lo < hi) {
        int mid = (lo + hi) >> 1;
        if (batch[mid] < g) lo = mid + 1; else hi = mid;
    }
    gstart[g] = lo;
}

// ---- Y[nrows,128] = X[nrows,128] @ W[128,128], fp32 ----
__global__ __launch_bounds__(256, 1) void k_gemm128(const float* __restrict__ X,
                                                    const float* __restrict__ W,
                                                    float* __restrict__ Y,
                                                    int nrows) {
    __shared__ float Wl[128 * 128];
    __shared__ float xT[128][36];
    const int tid = threadIdx.x;
    for (int i = tid; i < 128 * 128 / 4; i += 256)
        ((float4*)Wl)[i] = ((const float4*)W)[i];
    const int wave = tid >> 6, lane = tid & 63, rb = wave * 8;
    const int ntiles = (nrows + 31) / 32;
    for (int tile = blockIdx.x; tile < ntiles; tile += gridDim.x) {
        const int r0 = tile * 32;
        __syncthreads();
        for (int i = tid; i < 1024; i += 256) {
            int r = i >> 5, c4 = i & 31;
            float4 v = make_float4(0.f, 0.f, 0.f, 0.f);
            if (r0 + r < nrows) v = ((const float4*)(X + (size_t)(r0 + r) * 128))[c4];
            xT[c4 * 4 + 0][r] = v.x; xT[c4 * 4 + 1][r] = v.y;
            xT[c4 * 4 + 2][r] = v.z; xT[c4 * 4 + 3][r] = v.w;
        }
        __syncthreads();
        float acc[8][2];
#pragma unroll
        for (int r = 0; r < 8; r++) { acc[r][0] = 0.f; acc[r][1] = 0.f; }
#pragma unroll 4
        for (int k = 0; k < 128; k++) {
            float w0 = Wl[k * 128 + lane];
            float w1 = Wl[k * 128 + 64 + lane];
#pragma unroll
            for (int r = 0; r < 8; r++) {
                float xv = xT[k][rb + r];
                acc[r][0] = fmaf(xv, w0, acc[r][0]);
                acc[r][1] = fmaf(xv, w1, acc[r][1]);
            }
        }
#pragma unroll
        for (int r = 0; r < 8; r++) {
            int row = r0 + rb + r;
            if (row < nrows) {
                Y[(size_t)row * 128 + lane] = acc[r][0];
                Y[(size_t)row * 128 + 64 + lane] = acc[r][1];
            }
        }
    }
}

// ---- gather-aggregate + self-loop + bias + relu, one wave per node ----
__global__ __launch_bounds__(256) void k_gather(const float* __restrict__ XW,
                                                const int* __restrict__ rowptr,
                                                const int2* __restrict__ bucket,
                                                const float* __restrict__ dinv,
                                                const float* __restrict__ b,
                                                float* __restrict__ H) {
    const int wave = threadIdx.x >> 6, lane = threadIdx.x & 63;
    const int n = blockIdx.x * 4 + wave;
    if (n >= NN) return;
    const float di = dinv[n];
    const float sl = di * di;
    const float* xr = XW + (size_t)n * 128;
    float acc0 = xr[lane] * sl;
    float acc1 = xr[64 + lane] * sl;
    const int e1 = rowptr[n + 1];
    for (int e = rowptr[n]; e < e1; e++) {
        int2 p = bucket[e];
        float nm = __int_as_float(p.y);
        const float* r = XW + (size_t)p.x * 128;
        acc0 = fmaf(r[lane], nm, acc0);
        acc1 = fmaf(r[64 + lane], nm, acc1);
    }
    H[(size_t)n * 128 + lane]      = fmaxf(acc0 + b[lane], 0.f);
    H[(size_t)n * 128 + 64 + lane] = fmaxf(acc1 + b[64 + lane], 0.f);
}

// ---- pooling over sorted batch ranges: 8 node-slices per graph ----
__global__ __launch_bounds__(128) void k_pool2(const float* __restrict__ H,
                                               const int* __restrict__ gstart,
                                               float* __restrict__ MX,
                                               float* __restrict__ SM) {
    const int g = blockIdx.x >> 3, slice = blockIdx.x & 7;
    const int f = threadIdx.x;
    const int n0 = gstart[g], n1 = gstart[g + 1];
    float mx = 0.f, sm = 0.f;  // h >= 0 post-relu, so 0 is a valid max identity
    for (int n = n0 + slice; n < n1; n += 8) {
        float v = H[(size_t)n * 128 + f];
        mx = fmaxf(mx, v);
        sm += v;
    }
    atomicMax((unsigned int*)&MX[(size_t)g * 128 + f], __float_as_uint(mx));
    unsafeAtomicAdd(&SM[(size_t)g * 128 + f], sm);
}

// ---- head: z = [max, mean] @ linW + linb, log_softmax over 16 classes ----
__global__ __launch_bounds__(64) void k_final(const float* __restrict__ MX,
                                              const float* __restrict__ SM,
                                              const int* __restrict__ gstart,
                                              const float* __restrict__ linW,
                                              const float* __restrict__ linb,
                                              float* __restrict__ out) {
    int g = blockIdx.x, lane = threadIdx.x;
    if (lane < CC) {
        int cnt = gstart[g + 1] - gstart[g];
        float rc = 1.0f / fmaxf((float)cnt, 1.0f);
        float z = linb[lane];
        for (int f = 0; f < 128; f++) {
            z = fmaf(MX[(size_t)g * 128 + f], linW[f * CC + lane], z);
            z = fmaf(SM[(size_t)g * 128 + f] * rc, linW[(128 + f) * CC + lane], z);
        }
        float m = z;
        for (int o = 8; o >= 1; o >>= 1) m = fmaxf(m, __shfl_xor(m, o, 16));
        float ex = expf(z - m), s = ex;
        for (int o = 8; o >= 1; o >>= 1) s += __shfl_xor(s, o, 16);
        out[g * CC + lane] = z - m - logf(s);
    }
}

extern "C" void kernel_launch(void* const* d_in, const int* in_sizes, int n_in,
                              void* d_out, int out_size, void* d_ws, size_t ws_size,
                              hipStream_t stream) {
    const float* x    = (const float*)d_in[0];
    const int*   ei   = (const int*)d_in[1];
    const float* ew   = (const float*)d_in[2];
    const int*   batch= (const int*)d_in[3];
    const float* W1   = (const float*)d_in[4];
    const float* b1   = (const float*)d_in[5];
    const float* W2   = (const float*)d_in[6];
    const float* b2   = (const float*)d_in[7];
    const float* linW = (const float*)d_in[8];
    const float* linb = (const float*)d_in[9];
    float* out = (float*)d_out;

    // workspace layout
    float* A      = (float*)d_ws;                  // [N,128] xw
    float* B      = A + (size_t)NN * 128;          // [N,128] h
    int2*  BUCKET = (int2*)(B + (size_t)NN * 128); // [E] (src, norm bits)
    float* DEG    = (float*)(BUCKET + EE);         // [N] deg -> dinv
    int*   ROWPTR = (int*)(DEG + NN);              // [N+1]
    int*   CUR    = ROWPTR + NN + 1;               // [N] histogram -> cursor
    int*   GSTART = CUR + NN;                      // [G+1]
    float* MAXB   = (float*)(GSTART + GG + 1);     // [G,128]
    float* SUMB   = MAXB + (size_t)GG * 128;       // [G,128]
    int*   BS     = (int*)(SUMB + (size_t)GG * 128); // [NBLK]
    int*   BO     = BS + NBLK;                     // [NBLK]

    const int* src = ei;
    const int* dst = ei + EE;

    // zero the per-call accumulators
    hipMemsetAsync(DEG, 0, NN * sizeof(float), stream);
    hipMemsetAsync(CUR, 0, NN * sizeof(int), stream);
    hipMemsetAsync(MAXB, 0, (size_t)GG * 128 * 2 * sizeof(float), stream);

    // CSR build (shared by both layers)
    k_deg<<<1024, 256, 0, stream>>>(dst, ew, DEG, CUR);
    k_dinv<<<(NN + 255) / 256, 256, 0, stream>>>(DEG);
    k_scanA<<<NBLK, 256, 0, stream>>>(CUR, BS);
    k_scanB<<<1, 256, 0, stream>>>(BS, BO);
    k_scanC<<<NBLK, 256, 0, stream>>>(BO, ROWPTR, CUR);
    k_binfill<<<1024, 256, 0, stream>>>(src, dst, ew, DEG, CUR, BUCKET);
    k_gstart<<<1, 256, 0, stream>>>(batch, GSTART);

    // layer 1
    k_gemm128<<<1563, 256, 0, stream>>>(x, W1, A, NN);
    k_gather<<<(NN + 3) / 4, 256, 0, stream>>>(A, ROWPTR, BUCKET, DEG, b1, B);

    // layer 2
    k_gemm128<<<1563, 256, 0, stream>>>(B, W2, A, NN);
    k_gather<<<(NN + 3) / 4, 256, 0, stream>>>(A, ROWPTR, BUCKET, DEG, b2, B);

    // pooling + head
    k_pool2<<<GG * 8, 128, 0, stream>>>(B, GSTART, MAXB, SUMB);
    k_final<<<GG, 64, 0, stream>>>(MAXB, SUMB, GSTART, linW, linb, out);
}

// Round 4
// 303.938 us; speedup vs baseline: 3.4201x; 1.3835x over previous
//
#include <hip/hip_runtime.h>
#include <hip/hip_bf16.h>

#define NN 50000
#define EE 600000
#define FH 128
#define GG 128
#define CC 16
#define NBLK ((NN + 255) / 256)   // 196 scan blocks

typedef __attribute__((ext_vector_type(8))) short bf16x8;
typedef __attribute__((ext_vector_type(4))) float f32x4;

static __device__ __forceinline__ unsigned short f2bf(float f) {
    union { float f; unsigned int u; } v; v.f = f;
    unsigned int r = v.u + 0x7fffu + ((v.u >> 16) & 1u);   // RNE
    return (unsigned short)(r >> 16);
}
static __device__ __forceinline__ float bf2f(unsigned short h) {
    union { unsigned int u; float f; } v; v.u = ((unsigned int)h) << 16;
    return v.f;
}

// ---- degree (weighted, float) + in-degree (int) histogram over dst ----
__global__ __launch_bounds__(256) void k_deg(const int* __restrict__ dst,
                                             const float* __restrict__ ew,
                                             float* __restrict__ deg,
                                             int* __restrict__ cur) {
    for (int e = blockIdx.x * 256 + threadIdx.x; e < EE; e += gridDim.x * 256) {
        int d = dst[e];
        unsafeAtomicAdd(&deg[d], ew[e]);
        atomicAdd(&cur[d], 1);
    }
}

// ---- dinv = rsqrt(deg + 1) in place ----
__global__ __launch_bounds__(256) void k_dinv(float* __restrict__ deg) {
    int n = blockIdx.x * 256 + threadIdx.x;
    if (n < NN) deg[n] = rsqrtf(deg[n] + 1.0f);
}

// ---- multi-block exclusive scan of cur[] (3 phases) ----
__global__ __launch_bounds__(256) void k_scanA(const int* __restrict__ cur,
                                               int* __restrict__ bs) {
    int i = blockIdx.x * 256 + threadIdx.x;
    int v = (i < NN) ? cur[i] : 0;
#pragma unroll
    for (int o = 32; o >= 1; o >>= 1) v += __shfl_down(v, o, 64);
    __shared__ int ws[4];
    if ((threadIdx.x & 63) == 0) ws[threadIdx.x >> 6] = v;
    __syncthreads();
    if (threadIdx.x == 0) bs[blockIdx.x] = ws[0] + ws[1] + ws[2] + ws[3];
}

__global__ __launch_bounds__(256) void k_scanB(const int* __restrict__ bs,
                                               int* __restrict__ bo) {
    __shared__ int s[256];
    int t = threadIdx.x;
    int v = (t < NBLK) ? bs[t] : 0;
    s[t] = v;
    __syncthreads();
    for (int off = 1; off < 256; off <<= 1) {
        int add = (t >= off) ? s[t - off] : 0;
        __syncthreads();
        s[t] += add;
        __syncthreads();
    }
    if (t < NBLK) bo[t] = s[t] - v;
}

__global__ __launch_bounds__(256) void k_scanC(const int* __restrict__ bo,
                                               int* __restrict__ rowptr,
                                               int* __restrict__ cur) {
    __shared__ int s[256];
    int t = threadIdx.x;
    int i = blockIdx.x * 256 + t;
    int v = (i < NN) ? cur[i] : 0;
    s[t] = v;
    __syncthreads();
    for (int off = 1; off < 256; off <<= 1) {
        int add = (t >= off) ? s[t - off] : 0;
        __syncthreads();
        s[t] += add;
        __syncthreads();
    }
    int excl = s[t] - v + bo[blockIdx.x];
    if (i < NN) { rowptr[i] = excl; cur[i] = excl; }
    if (i == 0) rowptr[NN] = EE;
}

// ---- fill CSR buckets with (src, norm) pairs ----
__global__ __launch_bounds__(256) void k_binfill(const int* __restrict__ src,
                                                 const int* __restrict__ dst,
                                                 const float* __restrict__ ew,
                                                 const float* __restrict__ dinv,
                                                 int* __restrict__ cur,
                                                 int2* __restrict__ bucket) {
    for (int e = blockIdx.x * 256 + threadIdx.x; e < EE; e += gridDim.x * 256) {
        int s = src[e], d = dst[e];
        float nm = dinv[s] * ew[e] * dinv[d];
        int pos = atomicAdd(&cur[d], 1);
        bucket[pos] = make_int2(s, __float_as_int(nm));
    }
}

// ---- graph start offsets ----
__global__ __launch_bounds__(256) void k_gstart(const int* __restrict__ batch,
                                                int* __restrict__ gstart) {
    int g = threadIdx.x;
    if (g > GG) return;
    int lo = 0, hi = NN;
    while (lo < hi) {
        int mid = (lo + hi) >> 1;
        if (batch[mid] < g) lo = mid + 1; else hi = mid;
    }
    gstart[g] = lo;
}

// ---- W prep: Wt[c][k] = bf16(W[k][c]) ----
__global__ __launch_bounds__(256) void k_wprep(const float* __restrict__ W,
                                               unsigned short* __restrict__ Wt) {
    int o = blockIdx.x * 256 + threadIdx.x;
    if (o < 128 * 128) {
        int c = o >> 7, k = o & 127;
        Wt[o] = f2bf(W[k * 128 + c]);
    }
}

// ---- MFMA GEMM: Y[bf16, nrows x 128] = Xin @ W (Wt pre-transposed bf16) ----
// 128x128 tile / block, 4 waves, 64x64 per wave, K=128 in one LDS stage.
// LDS tiles XOR-swizzled: byte ^= (row&7)<<4  (conflict-free ds_read_b128).
template<int IN_F32>
__global__ __launch_bounds__(256, 2) void k_gemm_mfma(const void* __restrict__ Xin,
                                                      const unsigned short* __restrict__ Wt,
                                                      unsigned short* __restrict__ Y,
                                                      int nrows) {
    __shared__ char smem[65536];     // [0,32K)=Wl  [32K,64K)=Xl ; epilogue bounce aliases
    const int tid = threadIdx.x;
    const int r0 = blockIdx.x * 128;

    // stage Wt and X tile (2048 16B-chunks each, 8 per thread)
#pragma unroll
    for (int j = 0; j < 8; j++) {
        int ci = tid + 256 * j;                // 0..2047
        int row = ci >> 4, slot = ci & 15;
        int loff = row * 256 + ((slot * 16) ^ ((row & 7) << 4));
        *(uint4*)(smem + loff) = ((const uint4*)Wt)[ci];
        uint4 xv;
        int grow = r0 + row;
        if (IN_F32) {
            float4 f0 = make_float4(0.f, 0.f, 0.f, 0.f), f1 = f0;
            if (grow < nrows) {
                const float4* xp = (const float4*)((const float*)Xin + (size_t)grow * 128 + slot * 8);
                f0 = xp[0]; f1 = xp[1];
            }
            xv.x = (unsigned)f2bf(f0.x) | ((unsigned)f2bf(f0.y) << 16);
            xv.y = (unsigned)f2bf(f0.z) | ((unsigned)f2bf(f0.w) << 16);
            xv.z = (unsigned)f2bf(f1.x) | ((unsigned)f2bf(f1.y) << 16);
            xv.w = (unsigned)f2bf(f1.z) | ((unsigned)f2bf(f1.w) << 16);
        } else {
            xv = (grow < nrows)
               ? ((const uint4*)((const unsigned short*)Xin + (size_t)grow * 128))[slot]
               : make_uint4(0u, 0u, 0u, 0u);
        }
        *(uint4*)(smem + 32768 + loff) = xv;
    }
    __syncthreads();

    const int lane = tid & 63, w = tid >> 6;
    const int wr = (w >> 1) * 64, wc = (w & 1) * 64;
    const int lr = lane & 15, lg = lane >> 4;
    f32x4 acc[4][4];
#pragma unroll
    for (int a = 0; a < 4; a++)
#pragma unroll
        for (int c = 0; c < 4; c++) acc[a][c] = (f32x4){0.f, 0.f, 0.f, 0.f};

#pragma unroll
    for (int t = 0; t < 4; t++) {
        const int kb = t * 64 + lg * 16;
        bf16x8 af[4], bf[4];
#pragma unroll
        for (int i = 0; i < 4; i++) {
            int ar = wr + i * 16 + lr;
            af[i] = *(const bf16x8*)(smem + 32768 + ar * 256 + (kb ^ ((ar & 7) << 4)));
            int bc = wc + i * 16 + lr;
            bf[i] = *(const bf16x8*)(smem + bc * 256 + (kb ^ ((bc & 7) << 4)));
        }
#pragma unroll
        for (int fr = 0; fr < 4; fr++)
#pragma unroll
            for (int fc = 0; fc < 4; fc++)
                acc[fr][fc] = __builtin_amdgcn_mfma_f32_16x16x32_bf16(af[fr], bf[fc], acc[fr][fc], 0, 0, 0);
    }

    // epilogue: bounce through LDS (pitch 272B) for coalesced bf16 stores
    __syncthreads();
#pragma unroll
    for (int fr = 0; fr < 4; fr++)
#pragma unroll
        for (int fc = 0; fc < 4; fc++)
#pragma unroll
            for (int j = 0; j < 4; j++) {
                int row = wr + fr * 16 + lg * 4 + j;
                int col = wc + fc * 16 + lr;
                *(unsigned short*)(smem + row * 272 + col * 2) = f2bf(acc[fr][fc][j]);
            }
    __syncthreads();
#pragma unroll
    for (int j = 0; j < 8; j++) {
        int ci = tid + 256 * j;
        int row = ci >> 4, slot = ci & 15;
        int grow = r0 + row;
        if (grow < nrows)
            ((uint4*)(Y + (size_t)grow * 128))[slot] = *(const uint4*)(smem + row * 272 + slot * 16);
    }
}

// ---- gather-aggregate + self-loop + bias + relu (bf16 in, bf16 out) ----
__global__ __launch_bounds__(256) void k_gather(const unsigned short* __restrict__ XW,
                                                const int* __restrict__ rowptr,
                                                const int2* __restrict__ bucket,
                                                const float* __restrict__ dinv,
                                                const float* __restrict__ b,
                                                unsigned short* __restrict__ H) {
    const int wv = threadIdx.x >> 6, lane = threadIdx.x & 63;
    const int n = blockIdx.x * 4 + wv;
    if (n >= NN) return;
    const float di = dinv[n];
    const float sl = di * di;
    unsigned int u = *(const unsigned int*)(XW + (size_t)n * 128 + lane * 2);
    float acc0 = __uint_as_float(u << 16) * sl;
    float acc1 = __uint_as_float(u & 0xffff0000u) * sl;
    const int e1 = rowptr[n + 1];
    for (int e = rowptr[n]; e < e1; e++) {
        int2 p = bucket[e];
        float nm = __int_as_float(p.y);
        unsigned int v = *(const unsigned int*)(XW + (size_t)p.x * 128 + lane * 2);
        acc0 = fmaf(__uint_as_float(v << 16), nm, acc0);
        acc1 = fmaf(__uint_as_float(v & 0xffff0000u), nm, acc1);
    }
    float o0 = fmaxf(acc0 + b[lane * 2], 0.f);
    float o1 = fmaxf(acc1 + b[lane * 2 + 1], 0.f);
    unsigned int op = (unsigned)f2bf(o0) | ((unsigned)f2bf(o1) << 16);
    *(unsigned int*)(H + (size_t)n * 128 + lane * 2) = op;
}

// ---- pooling over sorted batch ranges (bf16 input) ----
__global__ __launch_bounds__(128) void k_pool2(const unsigned short* __restrict__ H,
                                               const int* __restrict__ gstart,
                                               float* __restrict__ MX,
                                               float* __restrict__ SM) {
    const int g = blockIdx.x >> 3, slice = blockIdx.x & 7;
    const int f = threadIdx.x;
    const int n0 = gstart[g], n1 = gstart[g + 1];
    float mx = 0.f, sm = 0.f;  // h >= 0 post-relu
    for (int n = n0 + slice; n < n1; n += 8) {
        float v = bf2f(H[(size_t)n * 128 + f]);
        mx = fmaxf(mx, v);
        sm += v;
    }
    atomicMax((unsigned int*)&MX[(size_t)g * 128 + f], __float_as_uint(mx));
    unsafeAtomicAdd(&SM[(size_t)g * 128 + f], sm);
}

// ---- head ----
__global__ __launch_bounds__(64) void k_final(const float* __restrict__ MX,
                                              const float* __restrict__ SM,
                                              const int* __restrict__ gstart,
                                              const float* __restrict__ linW,
                                              const float* __restrict__ linb,
                                              float* __restrict__ out) {
    int g = blockIdx.x, lane = threadIdx.x;
    if (lane < CC) {
        int cnt = gstart[g + 1] - gstart[g];
        float rc = 1.0f / fmaxf((float)cnt, 1.0f);
        float z = linb[lane];
        for (int f = 0; f < 128; f++) {
            z = fmaf(MX[(size_t)g * 128 + f], linW[f * CC + lane], z);
            z = fmaf(SM[(size_t)g * 128 + f] * rc, linW[(128 + f) * CC + lane], z);
        }
        float m = z;
        for (int o = 8; o >= 1; o >>= 1) m = fmaxf(m, __shfl_xor(m, o, 16));
        float ex = expf(z - m), s = ex;
        for (int o = 8; o >= 1; o >>= 1) s += __shfl_xor(s, o, 16);
        out[g * CC + lane] = z - m - logf(s);
    }
}

extern "C" void kernel_launch(void* const* d_in, const int* in_sizes, int n_in,
                              void* d_out, int out_size, void* d_ws, size_t ws_size,
                              hipStream_t stream) {
    const float* x    = (const float*)d_in[0];
    const int*   ei   = (const int*)d_in[1];
    const float* ew   = (const float*)d_in[2];
    const int*   batch= (const int*)d_in[3];
    const float* W1   = (const float*)d_in[4];
    const float* b1   = (const float*)d_in[5];
    const float* W2   = (const float*)d_in[6];
    const float* b2   = (const float*)d_in[7];
    const float* linW = (const float*)d_in[8];
    const float* linb = (const float*)d_in[9];
    float* out = (float*)d_out;

    // workspace layout
    unsigned short* YB = (unsigned short*)d_ws;            // [N,128] bf16 gemm out
    unsigned short* HB = YB + (size_t)NN * 128;            // [N,128] bf16 gather out
    int2*  BUCKET = (int2*)(HB + (size_t)NN * 128);        // [E]
    float* DEG    = (float*)(BUCKET + EE);                 // [N]
    int*   ROWPTR = (int*)(DEG + NN);                      // [N+1]
    int*   CUR    = ROWPTR + NN + 1;                       // [N]
    int*   GSTART = CUR + NN;                              // [G+1]
    float* MAXB   = (float*)(GSTART + GG + 1);             // [G,128]
    float* SUMB   = MAXB + (size_t)GG * 128;               // [G,128]
    int*   BS     = (int*)(SUMB + (size_t)GG * 128);       // [NBLK]
    int*   BO     = BS + NBLK;                             // [NBLK]
    unsigned short* WT1 = (unsigned short*)(BO + NBLK);    // [128*128]
    unsigned short* WT2 = WT1 + 128 * 128;                 // [128*128]

    const int* src = ei;
    const int* dst = ei + EE;

    hipMemsetAsync(DEG, 0, NN * sizeof(float), stream);
    hipMemsetAsync(CUR, 0, NN * sizeof(int), stream);
    hipMemsetAsync(MAXB, 0, (size_t)GG * 128 * 2 * sizeof(float), stream);

    // CSR build + W prep
    k_deg<<<1024, 256, 0, stream>>>(dst, ew, DEG, CUR);
    k_dinv<<<(NN + 255) / 256, 256, 0, stream>>>(DEG);
    k_scanA<<<NBLK, 256, 0, stream>>>(CUR, BS);
    k_scanB<<<1, 256, 0, stream>>>(BS, BO);
    k_scanC<<<NBLK, 256, 0, stream>>>(BO, ROWPTR, CUR);
    k_binfill<<<1024, 256, 0, stream>>>(src, dst, ew, DEG, CUR, BUCKET);
    k_gstart<<<1, 256, 0, stream>>>(batch, GSTART);
    k_wprep<<<64, 256, 0, stream>>>(W1, WT1);
    k_wprep<<<64, 256, 0, stream>>>(W2, WT2);

    const int gblk = (NN + 127) / 128;  // 391

    // layer 1
    k_gemm_mfma<1><<<gblk, 256, 0, stream>>>((const void*)x, WT1, YB, NN);
    k_gather<<<(NN + 3) / 4, 256, 0, stream>>>(YB, ROWPTR, BUCKET, DEG, b1, HB);

    // layer 2
    k_gemm_mfma<0><<<gblk, 256, 0, stream>>>((const void*)HB, WT2, YB, NN);
    k_gather<<<(NN + 3) / 4, 256, 0, stream>>>(YB, ROWPTR, BUCKET, DEG, b2, HB);

    // pooling + head
    k_pool2<<<GG * 8, 128, 0, stream>>>(HB, GSTART, MAXB, SUMB);
    k_final<<<GG, 64, 0, stream>>>(MAXB, SUMB, GSTART, linW, linb, out);
}

// Round 5
// 243.052 us; speedup vs baseline: 4.2768x; 1.2505x over previous
//
#include <hip/hip_runtime.h>
#include <hip/hip_bf16.h>

#define NN 50000
#define EE 600000
#define FH 128
#define GG 128
#define CC 16
#define NBLK ((NN + 255) / 256)   // 196 scan blocks

typedef __attribute__((ext_vector_type(8))) short bf16x8;
typedef __attribute__((ext_vector_type(4))) float f32x4;

static __device__ __forceinline__ unsigned short f2bf(float f) {
    union { float f; unsigned int u; } v; v.f = f;
    unsigned int r = v.u + 0x7fffu + ((v.u >> 16) & 1u);   // RNE
    return (unsigned short)(r >> 16);
}
static __device__ __forceinline__ float bf2f(unsigned short h) {
    union { unsigned int u; float f; } v; v.u = ((unsigned int)h) << 16;
    return v.f;
}

// ---- degree (weighted, float) + in-degree (int) histogram over dst ----
__global__ __launch_bounds__(256) void k_deg(const int* __restrict__ dst,
                                             const float* __restrict__ ew,
                                             float* __restrict__ deg,
                                             int* __restrict__ cur) {
    for (int e = blockIdx.x * 256 + threadIdx.x; e < EE; e += gridDim.x * 256) {
        int d = dst[e];
        unsafeAtomicAdd(&deg[d], ew[e]);
        atomicAdd(&cur[d], 1);
    }
}

// ---- dinv = rsqrt(deg + 1) in place ----
__global__ __launch_bounds__(256) void k_dinv(float* __restrict__ deg) {
    int n = blockIdx.x * 256 + threadIdx.x;
    if (n < NN) deg[n] = rsqrtf(deg[n] + 1.0f);
}

// ---- multi-block exclusive scan of cur[] (3 phases) ----
__global__ __launch_bounds__(256) void k_scanA(const int* __restrict__ cur,
                                               int* __restrict__ bs) {
    int i = blockIdx.x * 256 + threadIdx.x;
    int v = (i < NN) ? cur[i] : 0;
#pragma unroll
    for (int o = 32; o >= 1; o >>= 1) v += __shfl_down(v, o, 64);
    __shared__ int ws[4];
    if ((threadIdx.x & 63) == 0) ws[threadIdx.x >> 6] = v;
    __syncthreads();
    if (threadIdx.x == 0) bs[blockIdx.x] = ws[0] + ws[1] + ws[2] + ws[3];
}

__global__ __launch_bounds__(256) void k_scanB(const int* __restrict__ bs,
                                               int* __restrict__ bo) {
    __shared__ int s[256];
    int t = threadIdx.x;
    int v = (t < NBLK) ? bs[t] : 0;
    s[t] = v;
    __syncthreads();
    for (int off = 1; off < 256; off <<= 1) {
        int add = (t >= off) ? s[t - off] : 0;
        __syncthreads();
        s[t] += add;
        __syncthreads();
    }
    if (t < NBLK) bo[t] = s[t] - v;
}

__global__ __launch_bounds__(256) void k_scanC(const int* __restrict__ bo,
                                               int* __restrict__ rowptr,
                                               int* __restrict__ cur) {
    __shared__ int s[256];
    int t = threadIdx.x;
    int i = blockIdx.x * 256 + t;
    int v = (i < NN) ? cur[i] : 0;
    s[t] = v;
    __syncthreads();
    for (int off = 1; off < 256; off <<= 1) {
        int add = (t >= off) ? s[t - off] : 0;
        __syncthreads();
        s[t] += add;
        __syncthreads();
    }
    int excl = s[t] - v + bo[blockIdx.x];
    if (i < NN) { rowptr[i] = excl; cur[i] = excl; }
    if (i == 0) rowptr[NN] = EE;
}

// ---- fill CSR buckets with (src, norm) pairs ----
__global__ __launch_bounds__(256) void k_binfill(const int* __restrict__ src,
                                                 const int* __restrict__ dst,
                                                 const float* __restrict__ ew,
                                                 const float* __restrict__ dinv,
                                                 int* __restrict__ cur,
                                                 int2* __restrict__ bucket) {
    for (int e = blockIdx.x * 256 + threadIdx.x; e < EE; e += gridDim.x * 256) {
        int s = src[e], d = dst[e];
        float nm = dinv[s] * ew[e] * dinv[d];
        int pos = atomicAdd(&cur[d], 1);
        bucket[pos] = make_int2(s, __float_as_int(nm));
    }
}

// ---- graph start offsets ----
__global__ __launch_bounds__(256) void k_gstart(const int* __restrict__ batch,
                                                int* __restrict__ gstart) {
    int g = threadIdx.x;
    if (g > GG) return;
    int lo = 0, hi = NN;
    while (lo < hi) {
        int mid = (lo + hi) >> 1;
        if (batch[mid] < g) lo = mid + 1; else hi = mid;
    }
    gstart[g] = lo;
}

// ---- W prep: Wt[c][k] = bf16(W[k][c]) ----
__global__ __launch_bounds__(256) void k_wprep(const float* __restrict__ W,
                                               unsigned short* __restrict__ Wt) {
    int o = blockIdx.x * 256 + threadIdx.x;
    if (o < 128 * 128) {
        int c = o >> 7, k = o & 127;
        Wt[o] = f2bf(W[k * 128 + c]);
    }
}

// ---- MFMA GEMM: Y[bf16, nrows x 128] = Xin @ W (Wt pre-transposed bf16) ----
template<int IN_F32>
__global__ __launch_bounds__(256, 2) void k_gemm_mfma(const void* __restrict__ Xin,
                                                      const unsigned short* __restrict__ Wt,
                                                      unsigned short* __restrict__ Y,
                                                      int nrows) {
    __shared__ char smem[65536];     // [0,32K)=Wl  [32K,64K)=Xl ; epilogue bounce aliases
    const int tid = threadIdx.x;
    const int r0 = blockIdx.x * 128;

#pragma unroll
    for (int j = 0; j < 8; j++) {
        int ci = tid + 256 * j;                // 0..2047
        int row = ci >> 4, slot = ci & 15;
        int loff = row * 256 + ((slot * 16) ^ ((row & 7) << 4));
        *(uint4*)(smem + loff) = ((const uint4*)Wt)[ci];
        uint4 xv;
        int grow = r0 + row;
        if (IN_F32) {
            float4 f0 = make_float4(0.f, 0.f, 0.f, 0.f), f1 = f0;
            if (grow < nrows) {
                const float4* xp = (const float4*)((const float*)Xin + (size_t)grow * 128 + slot * 8);
                f0 = xp[0]; f1 = xp[1];
            }
            xv.x = (unsigned)f2bf(f0.x) | ((unsigned)f2bf(f0.y) << 16);
            xv.y = (unsigned)f2bf(f0.z) | ((unsigned)f2bf(f0.w) << 16);
            xv.z = (unsigned)f2bf(f1.x) | ((unsigned)f2bf(f1.y) << 16);
            xv.w = (unsigned)f2bf(f1.z) | ((unsigned)f2bf(f1.w) << 16);
        } else {
            xv = (grow < nrows)
               ? ((const uint4*)((const unsigned short*)Xin + (size_t)grow * 128))[slot]
               : make_uint4(0u, 0u, 0u, 0u);
        }
        *(uint4*)(smem + 32768 + loff) = xv;
    }
    __syncthreads();

    const int lane = tid & 63, w = tid >> 6;
    const int wr = (w >> 1) * 64, wc = (w & 1) * 64;
    const int lr = lane & 15, lg = lane >> 4;
    f32x4 acc[4][4];
#pragma unroll
    for (int a = 0; a < 4; a++)
#pragma unroll
        for (int c = 0; c < 4; c++) acc[a][c] = (f32x4){0.f, 0.f, 0.f, 0.f};

#pragma unroll
    for (int t = 0; t < 4; t++) {
        const int kb = t * 64 + lg * 16;
        bf16x8 af[4], bf[4];
#pragma unroll
        for (int i = 0; i < 4; i++) {
            int ar = wr + i * 16 + lr;
            af[i] = *(const bf16x8*)(smem + 32768 + ar * 256 + (kb ^ ((ar & 7) << 4)));
            int bc = wc + i * 16 + lr;
            bf[i] = *(const bf16x8*)(smem + bc * 256 + (kb ^ ((bc & 7) << 4)));
        }
#pragma unroll
        for (int fr = 0; fr < 4; fr++)
#pragma unroll
            for (int fc = 0; fc < 4; fc++)
                acc[fr][fc] = __builtin_amdgcn_mfma_f32_16x16x32_bf16(af[fr], bf[fc], acc[fr][fc], 0, 0, 0);
    }

    __syncthreads();
#pragma unroll
    for (int fr = 0; fr < 4; fr++)
#pragma unroll
        for (int fc = 0; fc < 4; fc++)
#pragma unroll
            for (int j = 0; j < 4; j++) {
                int row = wr + fr * 16 + lg * 4 + j;
                int col = wc + fc * 16 + lr;
                *(unsigned short*)(smem + row * 272 + col * 2) = f2bf(acc[fr][fc][j]);
            }
    __syncthreads();
#pragma unroll
    for (int j = 0; j < 8; j++) {
        int ci = tid + 256 * j;
        int row = ci >> 4, slot = ci & 15;
        int grow = r0 + row;
        if (grow < nrows)
            ((uint4*)(Y + (size_t)grow * 128))[slot] = *(const uint4*)(smem + row * 272 + slot * 16);
    }
}

// ---- gather-aggregate + self-loop + bias + relu (bf16 in/out) ----
// One wave per node; 4 edges in flight (16-lane group each); uint4 row loads.
__global__ __launch_bounds__(256) void k_gather(const unsigned short* __restrict__ XW,
                                                const int* __restrict__ rowptr,
                                                const int2* __restrict__ bucket,
                                                const float* __restrict__ dinv,
                                                const float* __restrict__ b,
                                                unsigned short* __restrict__ H) {
    const int wv = threadIdx.x >> 6, lane = threadIdx.x & 63;
    const int n = blockIdx.x * 4 + wv;
    if (n >= NN) return;
    const int eg = lane >> 4;        // edge group 0..3
    const int fl = lane & 15;        // 16B feature slot -> features 8*fl..8*fl+7
    const float di = dinv[n];
    const float sl = di * di;
    // self row (same load in all 4 groups; L1-resident)
    uint4 su = ((const uint4*)(XW + (size_t)n * 128))[fl];
    float acc[8];
#pragma unroll
    for (int q = 0; q < 8; q++) acc[q] = 0.f;
    const int e0 = rowptr[n], e1 = rowptr[n + 1];
    for (int e = e0 + eg; e < e1; e += 4) {
        int2 p = bucket[e];
        float nm = __int_as_float(p.y);
        uint4 v = ((const uint4*)(XW + (size_t)p.x * 128))[fl];
        unsigned int uu[4] = {v.x, v.y, v.z, v.w};
#pragma unroll
        for (int q = 0; q < 4; q++) {
            acc[2 * q]     = fmaf(__uint_as_float(uu[q] << 16), nm, acc[2 * q]);
            acc[2 * q + 1] = fmaf(__uint_as_float(uu[q] & 0xffff0000u), nm, acc[2 * q + 1]);
        }
    }
    // combine the 4 edge groups (full sum lands in every lane)
#pragma unroll
    for (int q = 0; q < 8; q++) {
        acc[q] += __shfl_xor(acc[q], 16);
        acc[q] += __shfl_xor(acc[q], 32);
    }
    // self-loop + bias + relu, pack, store (group 0 only: 16 lanes x 16B)
    if (eg == 0) {
        unsigned int us[4] = {su.x, su.y, su.z, su.w};
        float4 b0 = ((const float4*)b)[fl * 2];
        float4 b1 = ((const float4*)b)[fl * 2 + 1];
        float bb[8] = {b0.x, b0.y, b0.z, b0.w, b1.x, b1.y, b1.z, b1.w};
        float r[8];
#pragma unroll
        for (int q = 0; q < 4; q++) {
            r[2 * q]     = fmaxf(fmaf(__uint_as_float(us[q] << 16), sl, acc[2 * q]) + bb[2 * q], 0.f);
            r[2 * q + 1] = fmaxf(fmaf(__uint_as_float(us[q] & 0xffff0000u), sl, acc[2 * q + 1]) + bb[2 * q + 1], 0.f);
        }
        uint4 o;
        o.x = (unsigned)f2bf(r[0]) | ((unsigned)f2bf(r[1]) << 16);
        o.y = (unsigned)f2bf(r[2]) | ((unsigned)f2bf(r[3]) << 16);
        o.z = (unsigned)f2bf(r[4]) | ((unsigned)f2bf(r[5]) << 16);
        o.w = (unsigned)f2bf(r[6]) | ((unsigned)f2bf(r[7]) << 16);
        ((uint4*)(H + (size_t)n * 128))[fl] = o;
    }
}

// ---- pooling over sorted batch ranges (bf16 input) ----
__global__ __launch_bounds__(128) void k_pool2(const unsigned short* __restrict__ H,
                                               const int* __restrict__ gstart,
                                               float* __restrict__ MX,
                                               float* __restrict__ SM) {
    const int g = blockIdx.x >> 3, slice = blockIdx.x & 7;
    const int f = threadIdx.x;
    const int n0 = gstart[g], n1 = gstart[g + 1];
    float mx = 0.f, sm = 0.f;  // h >= 0 post-relu
    for (int n = n0 + slice; n < n1; n += 8) {
        float v = bf2f(H[(size_t)n * 128 + f]);
        mx = fmaxf(mx, v);
        sm += v;
    }
    atomicMax((unsigned int*)&MX[(size_t)g * 128 + f], __float_as_uint(mx));
    unsafeAtomicAdd(&SM[(size_t)g * 128 + f], sm);
}

// ---- head ----
__global__ __launch_bounds__(64) void k_final(const float* __restrict__ MX,
                                              const float* __restrict__ SM,
                                              const int* __restrict__ gstart,
                                              const float* __restrict__ linW,
                                              const float* __restrict__ linb,
                                              float* __restrict__ out) {
    int g = blockIdx.x, lane = threadIdx.x;
    if (lane < CC) {
        int cnt = gstart[g + 1] - gstart[g];
        float rc = 1.0f / fmaxf((float)cnt, 1.0f);
        float z = linb[lane];
        for (int f = 0; f < 128; f++) {
            z = fmaf(MX[(size_t)g * 128 + f], linW[f * CC + lane], z);
            z = fmaf(SM[(size_t)g * 128 + f] * rc, linW[(128 + f) * CC + lane], z);
        }
        float m = z;
        for (int o = 8; o >= 1; o >>= 1) m = fmaxf(m, __shfl_xor(m, o, 16));
        float ex = expf(z - m), s = ex;
        for (int o = 8; o >= 1; o >>= 1) s += __shfl_xor(s, o, 16);
        out[g * CC + lane] = z - m - logf(s);
    }
}

extern "C" void kernel_launch(void* const* d_in, const int* in_sizes, int n_in,
                              void* d_out, int out_size, void* d_ws, size_t ws_size,
                              hipStream_t stream) {
    const float* x    = (const float*)d_in[0];
    const int*   ei   = (const int*)d_in[1];
    const float* ew   = (const float*)d_in[2];
    const int*   batch= (const int*)d_in[3];
    const float* W1   = (const float*)d_in[4];
    const float* b1   = (const float*)d_in[5];
    const float* W2   = (const float*)d_in[6];
    const float* b2   = (const float*)d_in[7];
    const float* linW = (const float*)d_in[8];
    const float* linb = (const float*)d_in[9];
    float* out = (float*)d_out;

    // workspace layout
    unsigned short* YB = (unsigned short*)d_ws;            // [N,128] bf16 gemm out
    unsigned short* HB = YB + (size_t)NN * 128;            // [N,128] bf16 gather out
    int2*  BUCKET = (int2*)(HB + (size_t)NN * 128);        // [E]
    float* DEG    = (float*)(BUCKET + EE);                 // [N]
    int*   ROWPTR = (int*)(DEG + NN);                      // [N+1]
    int*   CUR    = ROWPTR + NN + 1;                       // [N]
    int*   GSTART = CUR + NN;                              // [G+1]
    float* MAXB   = (float*)(GSTART + GG + 1);             // [G,128]
    float* SUMB   = MAXB + (size_t)GG * 128;               // [G,128]
    int*   BS     = (int*)(SUMB + (size_t)GG * 128);       // [NBLK]
    int*   BO     = BS + NBLK;                             // [NBLK]
    unsigned short* WT1 = (unsigned short*)(BO + NBLK);    // [128*128]
    unsigned short* WT2 = WT1 + 128 * 128;                 // [128*128]

    const int* src = ei;
    const int* dst = ei + EE;

    hipMemsetAsync(DEG, 0, NN * sizeof(float), stream);
    hipMemsetAsync(CUR, 0, NN * sizeof(int), stream);
    hipMemsetAsync(MAXB, 0, (size_t)GG * 128 * 2 * sizeof(float), stream);

    // CSR build + W prep
    k_deg<<<1024, 256, 0, stream>>>(dst, ew, DEG, CUR);
    k_dinv<<<(NN + 255) / 256, 256, 0, stream>>>(DEG);
    k_scanA<<<NBLK, 256, 0, stream>>>(CUR, BS);
    k_scanB<<<1, 256, 0, stream>>>(BS, BO);
    k_scanC<<<NBLK, 256, 0, stream>>>(BO, ROWPTR, CUR);
    k_binfill<<<1024, 256, 0, stream>>>(src, dst, ew, DEG, CUR, BUCKET);
    k_gstart<<<1, 256, 0, stream>>>(batch, GSTART);
    k_wprep<<<64, 256, 0, stream>>>(W1, WT1);
    k_wprep<<<64, 256, 0, stream>>>(W2, WT2);

    const int gblk = (NN + 127) / 128;  // 391

    // layer 1
    k_gemm_mfma<1><<<gblk, 256, 0, stream>>>((const void*)x, WT1, YB, NN);
    k_gather<<<(NN + 3) / 4, 256, 0, stream>>>(YB, ROWPTR, BUCKET, DEG, b1, HB);

    // layer 2
    k_gemm_mfma<0><<<gblk, 256, 0, stream>>>((const void*)HB, WT2, YB, NN);
    k_gather<<<(NN + 3) / 4, 256, 0, stream>>>(YB, ROWPTR, BUCKET, DEG, b2, HB);

    // pooling + head
    k_pool2<<<GG * 8, 128, 0, stream>>>(HB, GSTART, MAXB, SUMB);
    k_final<<<GG, 64, 0, stream>>>(MAXB, SUMB, GSTART, linW, linb, out);
}

// Round 6
// 183.280 us; speedup vs baseline: 5.6716x; 1.3261x over previous
//
#include <hip/hip_runtime.h>
#include <hip/hip_bf16.h>

#define NN 50000
#define EE 600000
#define FH 128
#define GG 128
#define CC 16
#define NBLK ((NN + 255) / 256)   // 196 scan blocks

typedef __attribute__((ext_vector_type(8))) short bf16x8;
typedef __attribute__((ext_vector_type(4))) float f32x4;

#define FIXS 1.099511627776e12f   // 2^40
#define FIXI (1.0f / 1.099511627776e12f)

static __device__ __forceinline__ unsigned short f2bf(float f) {
    union { float f; unsigned int u; } v; v.f = f;
    unsigned int r = v.u + 0x7fffu + ((v.u >> 16) & 1u);   // RNE
    return (unsigned short)(r >> 16);
}
static __device__ __forceinline__ float bf2f(unsigned short h) {
    union { unsigned int u; float f; } v; v.u = ((unsigned int)h) << 16;
    return v.f;
}

// ---- degree: one u64 atomic per edge packs {count:16 | ew*2^40:48}.
//      Returned old value's hi bits = this edge's rank within its dst bin. ----
__global__ __launch_bounds__(256) void k_deg(const int* __restrict__ dst,
                                             const float* __restrict__ ew,
                                             unsigned long long* __restrict__ degc,
                                             int* __restrict__ rank) {
    for (int e = blockIdx.x * 256 + threadIdx.x; e < EE; e += gridDim.x * 256) {
        int d = dst[e];
        unsigned long long enc = (1ULL << 48) | (unsigned long long)(ew[e] * FIXS);
        unsigned long long old = atomicAdd(&degc[d], enc);
        rank[e] = (int)(old >> 48);
    }
}

// ---- scanA: per-block sums of counts; also dinv = rsqrt(deg+1) ----
__global__ __launch_bounds__(256) void k_scanA(const unsigned long long* __restrict__ degc,
                                               int* __restrict__ bs,
                                               float* __restrict__ dinv) {
    int i = blockIdx.x * 256 + threadIdx.x;
    int v = 0;
    if (i < NN) {
        unsigned long long d = degc[i];
        v = (int)(d >> 48);
        float deg = (float)(d & 0xFFFFFFFFFFFFULL) * FIXI;
        dinv[i] = rsqrtf(deg + 1.0f);
    }
#pragma unroll
    for (int o = 32; o >= 1; o >>= 1) v += __shfl_down(v, o, 64);
    __shared__ int ws[4];
    if ((threadIdx.x & 63) == 0) ws[threadIdx.x >> 6] = v;
    __syncthreads();
    if (threadIdx.x == 0) bs[blockIdx.x] = ws[0] + ws[1] + ws[2] + ws[3];
}

// ---- scanB: exclusive scan of block sums; also gstart binary search ----
__global__ __launch_bounds__(256) void k_scanB(const int* __restrict__ bs,
                                               int* __restrict__ bo,
                                               const int* __restrict__ batch,
                                               int* __restrict__ gstart) {
    __shared__ int s[256];
    int t = threadIdx.x;
    int v = (t < NBLK) ? bs[t] : 0;
    s[t] = v;
    __syncthreads();
    for (int off = 1; off < 256; off <<= 1) {
        int add = (t >= off) ? s[t - off] : 0;
        __syncthreads();
        s[t] += add;
        __syncthreads();
    }
    if (t < NBLK) bo[t] = s[t] - v;
    if (t <= GG) {
        int lo = 0, hi = NN;
        while (lo < hi) {
            int mid = (lo + hi) >> 1;
            if (batch[mid] < t) lo = mid + 1; else hi = mid;
        }
        gstart[t] = lo;
    }
}

// ---- scanC: rowptr = global exclusive scan of counts ----
__global__ __launch_bounds__(256) void k_scanC(const int* __restrict__ bo,
                                               const unsigned long long* __restrict__ degc,
                                               int* __restrict__ rowptr) {
    __shared__ int s[256];
    int t = threadIdx.x;
    int i = blockIdx.x * 256 + t;
    int v = (i < NN) ? (int)(degc[i] >> 48) : 0;
    s[t] = v;
    __syncthreads();
    for (int off = 1; off < 256; off <<= 1) {
        int add = (t >= off) ? s[t - off] : 0;
        __syncthreads();
        s[t] += add;
        __syncthreads();
    }
    int excl = s[t] - v + bo[blockIdx.x];
    if (i < NN) rowptr[i] = excl;
    if (i == 0) rowptr[NN] = EE;
}

// ---- fill CSR buckets, no atomics: pos = rowptr[d] + rank[e] ----
__global__ __launch_bounds__(256) void k_binfill(const int* __restrict__ src,
                                                 const int* __restrict__ dst,
                                                 const float* __restrict__ ew,
                                                 const float* __restrict__ dinv,
                                                 const int* __restrict__ rowptr,
                                                 const int* __restrict__ rank,
                                                 int2* __restrict__ bucket) {
    for (int e = blockIdx.x * 256 + threadIdx.x; e < EE; e += gridDim.x * 256) {
        int s = src[e], d = dst[e];
        float nm = dinv[s] * ew[e] * dinv[d];
        bucket[rowptr[d] + rank[e]] = make_int2(s, __float_as_int(nm));
    }
}

// ---- W prep: Wt[c][k] = bf16(W[k][c]) for both layers ----
__global__ __launch_bounds__(256) void k_wprep2(const float* __restrict__ W1,
                                                const float* __restrict__ W2,
                                                unsigned short* __restrict__ WT1,
                                                unsigned short* __restrict__ WT2) {
    int o = blockIdx.x * 256 + threadIdx.x;
    const float* W = (o < 128 * 128) ? W1 : W2;
    unsigned short* WT = (o < 128 * 128) ? WT1 : WT2;
    int oo = o & (128 * 128 - 1);
    int c = oo >> 7, k = oo & 127;
    WT[oo] = f2bf(W[k * 128 + c]);
}

// ---- MFMA GEMM: Y[bf16, nrows x 128] = Xin @ W (Wt pre-transposed bf16) ----
template<int IN_F32>
__global__ __launch_bounds__(256, 2) void k_gemm_mfma(const void* __restrict__ Xin,
                                                      const unsigned short* __restrict__ Wt,
                                                      unsigned short* __restrict__ Y,
                                                      int nrows) {
    __shared__ char smem[65536];     // [0,32K)=Wl  [32K,64K)=Xl ; epilogue bounce aliases
    const int tid = threadIdx.x;
    const int r0 = blockIdx.x * 128;

#pragma unroll
    for (int j = 0; j < 8; j++) {
        int ci = tid + 256 * j;                // 0..2047
        int row = ci >> 4, slot = ci & 15;
        int loff = row * 256 + ((slot * 16) ^ ((row & 7) << 4));
        *(uint4*)(smem + loff) = ((const uint4*)Wt)[ci];
        uint4 xv;
        int grow = r0 + row;
        if (IN_F32) {
            float4 f0 = make_float4(0.f, 0.f, 0.f, 0.f), f1 = f0;
            if (grow < nrows) {
                const float4* xp = (const float4*)((const float*)Xin + (size_t)grow * 128 + slot * 8);
                f0 = xp[0]; f1 = xp[1];
            }
            xv.x = (unsigned)f2bf(f0.x) | ((unsigned)f2bf(f0.y) << 16);
            xv.y = (unsigned)f2bf(f0.z) | ((unsigned)f2bf(f0.w) << 16);
            xv.z = (unsigned)f2bf(f1.x) | ((unsigned)f2bf(f1.y) << 16);
            xv.w = (unsigned)f2bf(f1.z) | ((unsigned)f2bf(f1.w) << 16);
        } else {
            xv = (grow < nrows)
               ? ((const uint4*)((const unsigned short*)Xin + (size_t)grow * 128))[slot]
               : make_uint4(0u, 0u, 0u, 0u);
        }
        *(uint4*)(smem + 32768 + loff) = xv;
    }
    __syncthreads();

    const int lane = tid & 63, w = tid >> 6;
    const int wr = (w >> 1) * 64, wc = (w & 1) * 64;
    const int lr = lane & 15, lg = lane >> 4;
    f32x4 acc[4][4];
#pragma unroll
    for (int a = 0; a < 4; a++)
#pragma unroll
        for (int c = 0; c < 4; c++) acc[a][c] = (f32x4){0.f, 0.f, 0.f, 0.f};

#pragma unroll
    for (int t = 0; t < 4; t++) {
        const int kb = t * 64 + lg * 16;
        bf16x8 af[4], bf[4];
#pragma unroll
        for (int i = 0; i < 4; i++) {
            int ar = wr + i * 16 + lr;
            af[i] = *(const bf16x8*)(smem + 32768 + ar * 256 + (kb ^ ((ar & 7) << 4)));
            int bc = wc + i * 16 + lr;
            bf[i] = *(const bf16x8*)(smem + bc * 256 + (kb ^ ((bc & 7) << 4)));
        }
#pragma unroll
        for (int fr = 0; fr < 4; fr++)
#pragma unroll
            for (int fc = 0; fc < 4; fc++)
                acc[fr][fc] = __builtin_amdgcn_mfma_f32_16x16x32_bf16(af[fr], bf[fc], acc[fr][fc], 0, 0, 0);
    }

    __syncthreads();
#pragma unroll
    for (int fr = 0; fr < 4; fr++)
#pragma unroll
        for (int fc = 0; fc < 4; fc++)
#pragma unroll
            for (int j = 0; j < 4; j++) {
                int row = wr + fr * 16 + lg * 4 + j;
                int col = wc + fc * 16 + lr;
                *(unsigned short*)(smem + row * 272 + col * 2) = f2bf(acc[fr][fc][j]);
            }
    __syncthreads();
#pragma unroll
    for (int j = 0; j < 8; j++) {
        int ci = tid + 256 * j;
        int row = ci >> 4, slot = ci & 15;
        int grow = r0 + row;
        if (grow < nrows)
            ((uint4*)(Y + (size_t)grow * 128))[slot] = *(const uint4*)(smem + row * 272 + slot * 16);
    }
}

// ---- gather-aggregate + self-loop + bias + relu (bf16 in/out) ----
// One wave per node; 4 edges in flight (16-lane group each); uint4 row loads.
__global__ __launch_bounds__(256) void k_gather(const unsigned short* __restrict__ XW,
                                                const int* __restrict__ rowptr,
                                                const int2* __restrict__ bucket,
                                                const float* __restrict__ dinv,
                                                const float* __restrict__ b,
                                                unsigned short* __restrict__ H) {
    const int wv = threadIdx.x >> 6, lane = threadIdx.x & 63;
    const int n = blockIdx.x * 4 + wv;
    if (n >= NN) return;
    const int eg = lane >> 4;        // edge group 0..3
    const int fl = lane & 15;        // 16B feature slot -> features 8*fl..8*fl+7
    const float di = dinv[n];
    const float sl = di * di;
    uint4 su = ((const uint4*)(XW + (size_t)n * 128))[fl];
    float acc[8];
#pragma unroll
    for (int q = 0; q < 8; q++) acc[q] = 0.f;
    const int e0 = rowptr[n], e1 = rowptr[n + 1];
    for (int e = e0 + eg; e < e1; e += 4) {
        int2 p = bucket[e];
        float nm = __int_as_float(p.y);
        uint4 v = ((const uint4*)(XW + (size_t)p.x * 128))[fl];
        unsigned int uu[4] = {v.x, v.y, v.z, v.w};
#pragma unroll
        for (int q = 0; q < 4; q++) {
            acc[2 * q]     = fmaf(__uint_as_float(uu[q] << 16), nm, acc[2 * q]);
            acc[2 * q + 1] = fmaf(__uint_as_float(uu[q] & 0xffff0000u), nm, acc[2 * q + 1]);
        }
    }
#pragma unroll
    for (int q = 0; q < 8; q++) {
        acc[q] += __shfl_xor(acc[q], 16);
        acc[q] += __shfl_xor(acc[q], 32);
    }
    if (eg == 0) {
        unsigned int us[4] = {su.x, su.y, su.z, su.w};
        float4 b0 = ((const float4*)b)[fl * 2];
        float4 b1 = ((const float4*)b)[fl * 2 + 1];
        float bb[8] = {b0.x, b0.y, b0.z, b0.w, b1.x, b1.y, b1.z, b1.w};
        float r[8];
#pragma unroll
        for (int q = 0; q < 4; q++) {
            r[2 * q]     = fmaxf(fmaf(__uint_as_float(us[q] << 16), sl, acc[2 * q]) + bb[2 * q], 0.f);
            r[2 * q + 1] = fmaxf(fmaf(__uint_as_float(us[q] & 0xffff0000u), sl, acc[2 * q + 1]) + bb[2 * q + 1], 0.f);
        }
        uint4 o;
        o.x = (unsigned)f2bf(r[0]) | ((unsigned)f2bf(r[1]) << 16);
        o.y = (unsigned)f2bf(r[2]) | ((unsigned)f2bf(r[3]) << 16);
        o.z = (unsigned)f2bf(r[4]) | ((unsigned)f2bf(r[5]) << 16);
        o.w = (unsigned)f2bf(r[6]) | ((unsigned)f2bf(r[7]) << 16);
        ((uint4*)(H + (size_t)n * 128))[fl] = o;
    }
}

// ---- pooling over sorted batch ranges (bf16 input) ----
__global__ __launch_bounds__(128) void k_pool2(const unsigned short* __restrict__ H,
                                               const int* __restrict__ gstart,
                                               float* __restrict__ MX,
                                               float* __restrict__ SM) {
    const int g = blockIdx.x >> 3, slice = blockIdx.x & 7;
    const int f = threadIdx.x;
    const int n0 = gstart[g], n1 = gstart[g + 1];
    float mx = 0.f, sm = 0.f;  // h >= 0 post-relu
    for (int n = n0 + slice; n < n1; n += 8) {
        float v = bf2f(H[(size_t)n * 128 + f]);
        mx = fmaxf(mx, v);
        sm += v;
    }
    atomicMax((unsigned int*)&MX[(size_t)g * 128 + f], __float_as_uint(mx));
    unsafeAtomicAdd(&SM[(size_t)g * 128 + f], sm);
}

// ---- head ----
__global__ __launch_bounds__(64) void k_final(const float* __restrict__ MX,
                                              const float* __restrict__ SM,
                                              const int* __restrict__ gstart,
                                              const float* __restrict__ linW,
                                              const float* __restrict__ linb,
                                              float* __restrict__ out) {
    int g = blockIdx.x, lane = threadIdx.x;
    if (lane < CC) {
        int cnt = gstart[g + 1] - gstart[g];
        float rc = 1.0f / fmaxf((float)cnt, 1.0f);
        float z = linb[lane];
        for (int f = 0; f < 128; f++) {
            z = fmaf(MX[(size_t)g * 128 + f], linW[f * CC + lane], z);
            z = fmaf(SM[(size_t)g * 128 + f] * rc, linW[(128 + f) * CC + lane], z);
        }
        float m = z;
        for (int o = 8; o >= 1; o >>= 1) m = fmaxf(m, __shfl_xor(m, o, 16));
        float ex = expf(z - m), s = ex;
        for (int o = 8; o >= 1; o >>= 1) s += __shfl_xor(s, o, 16);
        out[g * CC + lane] = z - m - logf(s);
    }
}

extern "C" void kernel_launch(void* const* d_in, const int* in_sizes, int n_in,
                              void* d_out, int out_size, void* d_ws, size_t ws_size,
                              hipStream_t stream) {
    const float* x    = (const float*)d_in[0];
    const int*   ei   = (const int*)d_in[1];
    const float* ew   = (const float*)d_in[2];
    const int*   batch= (const int*)d_in[3];
    const float* W1   = (const float*)d_in[4];
    const float* b1   = (const float*)d_in[5];
    const float* W2   = (const float*)d_in[6];
    const float* b2   = (const float*)d_in[7];
    const float* linW = (const float*)d_in[8];
    const float* linb = (const float*)d_in[9];
    float* out = (float*)d_out;

    // workspace layout (8B-aligned blocks first)
    unsigned short* YB = (unsigned short*)d_ws;              // [N,128] bf16 gemm out
    unsigned short* HB = YB + (size_t)NN * 128;              // [N,128] bf16 gather out
    int2*  BUCKET = (int2*)(HB + (size_t)NN * 128);          // [E]
    unsigned long long* DEGC = (unsigned long long*)(BUCKET + EE);  // [N] packed
    float* DINV   = (float*)(DEGC + NN);                     // [N]
    int*   ROWPTR = (int*)(DINV + NN);                       // [N+1]
    int*   RANKE  = ROWPTR + NN + 1;                         // [E]
    int*   GSTART = RANKE + EE;                              // [G+1]
    float* MAXB   = (float*)(GSTART + GG + 1);               // [G,128]
    float* SUMB   = MAXB + (size_t)GG * 128;                 // [G,128]
    int*   BS     = (int*)(SUMB + (size_t)GG * 128);         // [NBLK]
    int*   BO     = BS + NBLK;                               // [NBLK]
    unsigned short* WT1 = (unsigned short*)(BO + NBLK);      // [128*128]
    unsigned short* WT2 = WT1 + 128 * 128;                   // [128*128]

    const int* src = ei;
    const int* dst = ei + EE;

    hipMemsetAsync(DEGC, 0, NN * sizeof(unsigned long long), stream);
    hipMemsetAsync(MAXB, 0, (size_t)GG * 128 * 2 * sizeof(float), stream);

    // CSR build + W prep
    k_deg<<<1024, 256, 0, stream>>>(dst, ew, DEGC, RANKE);
    k_scanA<<<NBLK, 256, 0, stream>>>(DEGC, BS, DINV);
    k_scanB<<<1, 256, 0, stream>>>(BS, BO, batch, GSTART);
    k_scanC<<<NBLK, 256, 0, stream>>>(BO, DEGC, ROWPTR);
    k_binfill<<<1024, 256, 0, stream>>>(src, dst, ew, DINV, ROWPTR, RANKE, BUCKET);
    k_wprep2<<<128, 256, 0, stream>>>(W1, W2, WT1, WT2);

    const int gblk = (NN + 127) / 128;  // 391

    // layer 1
    k_gemm_mfma<1><<<gblk, 256, 0, stream>>>((const void*)x, WT1, YB, NN);
    k_gather<<<(NN + 3) / 4, 256, 0, stream>>>(YB, ROWPTR, BUCKET, DINV, b1, HB);

    // layer 2
    k_gemm_mfma<0><<<gblk, 256, 0, stream>>>((const void*)HB, WT2, YB, NN);
    k_gather<<<(NN + 3) / 4, 256, 0, stream>>>(YB, ROWPTR, BUCKET, DINV, b2, HB);

    // pooling + head
    k_pool2<<<GG * 8, 128, 0, stream>>>(HB, GSTART, MAXB, SUMB);
    k_final<<<GG, 64, 0, stream>>>(MAXB, SUMB, GSTART, linW, linb, out);
}

// Round 7
// 174.770 us; speedup vs baseline: 5.9477x; 1.0487x over previous
//
#include <hip/hip_runtime.h>
#include <hip/hip_bf16.h>

#define NN 50000
#define EE 600000
#define FH 128
#define GG 128
#define CC 16
#define NBLK ((NN + 255) / 256)   // 196 scan blocks

typedef __attribute__((ext_vector_type(8))) short bf16x8;
typedef __attribute__((ext_vector_type(4))) float f32x4;

#define FIXS 1.099511627776e12f   // 2^40
#define FIXI (1.0f / 1.099511627776e12f)

static __device__ __forceinline__ unsigned short f2bf(float f) {
    union { float f; unsigned int u; } v; v.f = f;
    unsigned int r = v.u + 0x7fffu + ((v.u >> 16) & 1u);   // RNE
    return (unsigned short)(r >> 16);
}
static __device__ __forceinline__ float bf2f(unsigned short h) {
    union { unsigned int u; float f; } v; v.u = ((unsigned int)h) << 16;
    return v.f;
}

// ---- zero the per-call accumulators (replaces 2 hipMemsetAsync) ----
__global__ __launch_bounds__(256) void k_zero(unsigned long long* __restrict__ degc,
                                              float* __restrict__ maxsum) {
    int i = blockIdx.x * 256 + threadIdx.x;
    if (i < NN) degc[i] = 0ULL;
    if (i < GG * 128 * 2) maxsum[i] = 0.f;
}

// ---- degree: one u64 atomic per edge packs {count:16 | ew*2^40:48}.
//      Returned old value's hi bits = this edge's rank within its dst bin. ----
__global__ __launch_bounds__(256) void k_deg(const int* __restrict__ dst,
                                             const float* __restrict__ ew,
                                             unsigned long long* __restrict__ degc,
                                             int* __restrict__ rank) {
    int e = blockIdx.x * 256 + threadIdx.x;
    if (e < EE) {
        int d = dst[e];
        unsigned long long enc = (1ULL << 48) | (unsigned long long)(ew[e] * FIXS);
        unsigned long long old = atomicAdd(&degc[d], enc);
        rank[e] = (int)(old >> 48);
    }
}

// ---- scanA: per-block sums of counts; also dinv = rsqrt(deg+1) ----
__global__ __launch_bounds__(256) void k_scanA(const unsigned long long* __restrict__ degc,
                                               int* __restrict__ bs,
                                               float* __restrict__ dinv) {
    int i = blockIdx.x * 256 + threadIdx.x;
    int v = 0;
    if (i < NN) {
        unsigned long long d = degc[i];
        v = (int)(d >> 48);
        float deg = (float)(d & 0xFFFFFFFFFFFFULL) * FIXI;
        dinv[i] = rsqrtf(deg + 1.0f);
    }
#pragma unroll
    for (int o = 32; o >= 1; o >>= 1) v += __shfl_down(v, o, 64);
    __shared__ int ws[4];
    if ((threadIdx.x & 63) == 0) ws[threadIdx.x >> 6] = v;
    __syncthreads();
    if (threadIdx.x == 0) bs[blockIdx.x] = ws[0] + ws[1] + ws[2] + ws[3];
}

// ---- scanB: exclusive scan of block sums; also gstart binary search ----
__global__ __launch_bounds__(256) void k_scanB(const int* __restrict__ bs,
                                               int* __restrict__ bo,
                                               const int* __restrict__ batch,
                                               int* __restrict__ gstart) {
    __shared__ int s[256];
    int t = threadIdx.x;
    int v = (t < NBLK) ? bs[t] : 0;
    s[t] = v;
    __syncthreads();
    for (int off = 1; off < 256; off <<= 1) {
        int add = (t >= off) ? s[t - off] : 0;
        __syncthreads();
        s[t] += add;
        __syncthreads();
    }
    if (t < NBLK) bo[t] = s[t] - v;
    if (t <= GG) {
        int lo = 0, hi = NN;
        while (lo < hi) {
            int mid = (lo + hi) >> 1;
            if (batch[mid] < t) lo = mid + 1; else hi = mid;
        }
        gstart[t] = lo;
    }
}

// ---- scanC: rowptr = global exclusive scan of counts ----
__global__ __launch_bounds__(256) void k_scanC(const int* __restrict__ bo,
                                               const unsigned long long* __restrict__ degc,
                                               int* __restrict__ rowptr) {
    __shared__ int s[256];
    int t = threadIdx.x;
    int i = blockIdx.x * 256 + t;
    int v = (i < NN) ? (int)(degc[i] >> 48) : 0;
    s[t] = v;
    __syncthreads();
    for (int off = 1; off < 256; off <<= 1) {
        int add = (t >= off) ? s[t - off] : 0;
        __syncthreads();
        s[t] += add;
        __syncthreads();
    }
    int excl = s[t] - v + bo[blockIdx.x];
    if (i < NN) rowptr[i] = excl;
    if (i == 0) rowptr[NN] = EE;
}

// ---- fill CSR buckets, no atomics: pos = rowptr[d] + rank[e] ----
__global__ __launch_bounds__(256) void k_binfill(const int* __restrict__ src,
                                                 const int* __restrict__ dst,
                                                 const float* __restrict__ ew,
                                                 const float* __restrict__ dinv,
                                                 const int* __restrict__ rowptr,
                                                 const int* __restrict__ rank,
                                                 int2* __restrict__ bucket) {
    for (int e = blockIdx.x * 256 + threadIdx.x; e < EE; e += gridDim.x * 256) {
        int s = src[e], d = dst[e];
        float nm = dinv[s] * ew[e] * dinv[d];
        bucket[rowptr[d] + rank[e]] = make_int2(s, __float_as_int(nm));
    }
}

// ---- W prep: Wt[c][k] = bf16(W[k][c]) for both layers ----
__global__ __launch_bounds__(256) void k_wprep2(const float* __restrict__ W1,
                                                const float* __restrict__ W2,
                                                unsigned short* __restrict__ WT1,
                                                unsigned short* __restrict__ WT2) {
    int o = blockIdx.x * 256 + threadIdx.x;
    const float* W = (o < 128 * 128) ? W1 : W2;
    unsigned short* WT = (o < 128 * 128) ? WT1 : WT2;
    int oo = o & (128 * 128 - 1);
    int c = oo >> 7, k = oo & 127;
    WT[oo] = f2bf(W[k * 128 + c]);
}

// ---- MFMA GEMM: Y[bf16, nrows x 128] = Xin @ W (Wt pre-transposed bf16) ----
// 64-row tile / block (782 blocks -> good CU balance), 4 waves, 32x64 each.
// LDS 48KB -> 3 blocks/CU. XOR-swizzle: byte ^= (row&7)<<4.
template<int IN_F32>
__global__ __launch_bounds__(256, 3) void k_gemm_mfma(const void* __restrict__ Xin,
                                                      const unsigned short* __restrict__ Wt,
                                                      unsigned short* __restrict__ Y,
                                                      int nrows) {
    __shared__ char smem[49152];     // [0,32K)=Wl  [32K,48K)=Xl(64 rows); epilogue bounce aliases
    const int tid = threadIdx.x;
    const int r0 = blockIdx.x * 64;

    // stage: W = 2048 16B-chunks, X = 1024 chunks; 12 per thread
#pragma unroll
    for (int j = 0; j < 12; j++) {
        int ci = tid + 256 * j;
        if (ci < 2048) {             // W chunk
            int row = ci >> 4, slot = ci & 15;
            int loff = row * 256 + ((slot * 16) ^ ((row & 7) << 4));
            *(uint4*)(smem + loff) = ((const uint4*)Wt)[ci];
        } else {                     // X chunk
            int xci = ci - 2048;
            int row = xci >> 4, slot = xci & 15;
            int loff = 32768 + row * 256 + ((slot * 16) ^ ((row & 7) << 4));
            int grow = r0 + row;
            uint4 xv;
            if (IN_F32) {
                float4 f0 = make_float4(0.f, 0.f, 0.f, 0.f), f1 = f0;
                if (grow < nrows) {
                    const float4* xp = (const float4*)((const float*)Xin + (size_t)grow * 128 + slot * 8);
                    f0 = xp[0]; f1 = xp[1];
                }
                xv.x = (unsigned)f2bf(f0.x) | ((unsigned)f2bf(f0.y) << 16);
                xv.y = (unsigned)f2bf(f0.z) | ((unsigned)f2bf(f0.w) << 16);
                xv.z = (unsigned)f2bf(f1.x) | ((unsigned)f2bf(f1.y) << 16);
                xv.w = (unsigned)f2bf(f1.z) | ((unsigned)f2bf(f1.w) << 16);
            } else {
                xv = (grow < nrows)
                   ? ((const uint4*)((const unsigned short*)Xin + (size_t)grow * 128))[slot]
                   : make_uint4(0u, 0u, 0u, 0u);
            }
            *(uint4*)(smem + loff) = xv;
        }
    }
    __syncthreads();

    const int lane = tid & 63, w = tid >> 6;
    const int wr = (w >> 1) * 32, wc = (w & 1) * 64;   // 32 rows x 64 cols per wave
    const int lr = lane & 15, lg = lane >> 4;
    f32x4 acc[2][4];
#pragma unroll
    for (int a = 0; a < 2; a++)
#pragma unroll
        for (int c = 0; c < 4; c++) acc[a][c] = (f32x4){0.f, 0.f, 0.f, 0.f};

#pragma unroll
    for (int t = 0; t < 4; t++) {
        const int kb = t * 64 + lg * 16;
        bf16x8 af[2], bf[4];
#pragma unroll
        for (int i = 0; i < 2; i++) {
            int ar = wr + i * 16 + lr;
            af[i] = *(const bf16x8*)(smem + 32768 + ar * 256 + (kb ^ ((ar & 7) << 4)));
        }
#pragma unroll
        for (int i = 0; i < 4; i++) {
            int bc = wc + i * 16 + lr;
            bf[i] = *(const bf16x8*)(smem + bc * 256 + (kb ^ ((bc & 7) << 4)));
        }
#pragma unroll
        for (int fr = 0; fr < 2; fr++)
#pragma unroll
            for (int fc = 0; fc < 4; fc++)
                acc[fr][fc] = __builtin_amdgcn_mfma_f32_16x16x32_bf16(af[fr], bf[fc], acc[fr][fc], 0, 0, 0);
    }

    // epilogue: bounce through LDS (pitch 272B) for coalesced bf16 stores
    __syncthreads();
#pragma unroll
    for (int fr = 0; fr < 2; fr++)
#pragma unroll
        for (int fc = 0; fc < 4; fc++)
#pragma unroll
            for (int j = 0; j < 4; j++) {
                int row = wr + fr * 16 + lg * 4 + j;
                int col = wc + fc * 16 + lr;
                *(unsigned short*)(smem + row * 272 + col * 2) = f2bf(acc[fr][fc][j]);
            }
    __syncthreads();
#pragma unroll
    for (int j = 0; j < 4; j++) {
        int ci = tid + 256 * j;
        int row = ci >> 4, slot = ci & 15;
        int grow = r0 + row;
        if (grow < nrows)
            ((uint4*)(Y + (size_t)grow * 128))[slot] = *(const uint4*)(smem + row * 272 + slot * 16);
    }
}

// ---- gather-aggregate + self-loop + bias + relu (bf16 in/out) ----
// One wave per node; 4 edge-groups x 2-deep unroll = 8 row loads in flight.
__global__ __launch_bounds__(256) void k_gather(const unsigned short* __restrict__ XW,
                                                const int* __restrict__ rowptr,
                                                const int2* __restrict__ bucket,
                                                const float* __restrict__ dinv,
                                                const float* __restrict__ b,
                                                unsigned short* __restrict__ H) {
    const int wv = threadIdx.x >> 6, lane = threadIdx.x & 63;
    const int n = blockIdx.x * 4 + wv;
    if (n >= NN) return;
    const int eg = lane >> 4;        // edge group 0..3
    const int fl = lane & 15;        // 16B feature slot -> features 8*fl..8*fl+7
    const float di = dinv[n];
    const float sl = di * di;
    uint4 su = ((const uint4*)(XW + (size_t)n * 128))[fl];
    float acc[8];
#pragma unroll
    for (int q = 0; q < 8; q++) acc[q] = 0.f;
    const int e0 = rowptr[n], e1 = rowptr[n + 1];
    int e = e0 + eg;
    for (; e + 4 < e1; e += 8) {     // 2 edges per group per iter
        int2 p0 = bucket[e];
        int2 p1 = bucket[e + 4];
        float nm0 = __int_as_float(p0.y);
        float nm1 = __int_as_float(p1.y);
        uint4 v0 = ((const uint4*)(XW + (size_t)p0.x * 128))[fl];
        uint4 v1 = ((const uint4*)(XW + (size_t)p1.x * 128))[fl];
        unsigned int u0[4] = {v0.x, v0.y, v0.z, v0.w};
        unsigned int u1[4] = {v1.x, v1.y, v1.z, v1.w};
#pragma unroll
        for (int q = 0; q < 4; q++) {
            acc[2 * q]     = fmaf(__uint_as_float(u0[q] << 16), nm0, acc[2 * q]);
            acc[2 * q + 1] = fmaf(__uint_as_float(u0[q] & 0xffff0000u), nm0, acc[2 * q + 1]);
            acc[2 * q]     = fmaf(__uint_as_float(u1[q] << 16), nm1, acc[2 * q]);
            acc[2 * q + 1] = fmaf(__uint_as_float(u1[q] & 0xffff0000u), nm1, acc[2 * q + 1]);
        }
    }
    if (e < e1) {                    // tail edge for this group
        int2 p = bucket[e];
        float nm = __int_as_float(p.y);
        uint4 v = ((const uint4*)(XW + (size_t)p.x * 128))[fl];
        unsigned int uu[4] = {v.x, v.y, v.z, v.w};
#pragma unroll
        for (int q = 0; q < 4; q++) {
            acc[2 * q]     = fmaf(__uint_as_float(uu[q] << 16), nm, acc[2 * q]);
            acc[2 * q + 1] = fmaf(__uint_as_float(uu[q] & 0xffff0000u), nm, acc[2 * q + 1]);
        }
    }
#pragma unroll
    for (int q = 0; q < 8; q++) {
        acc[q] += __shfl_xor(acc[q], 16);
        acc[q] += __shfl_xor(acc[q], 32);
    }
    if (eg == 0) {
        unsigned int us[4] = {su.x, su.y, su.z, su.w};
        float4 b0 = ((const float4*)b)[fl * 2];
        float4 b1 = ((const float4*)b)[fl * 2 + 1];
        float bb[8] = {b0.x, b0.y, b0.z, b0.w, b1.x, b1.y, b1.z, b1.w};
        float r[8];
#pragma unroll
        for (int q = 0; q < 4; q++) {
            r[2 * q]     = fmaxf(fmaf(__uint_as_float(us[q] << 16), sl, acc[2 * q]) + bb[2 * q], 0.f);
            r[2 * q + 1] = fmaxf(fmaf(__uint_as_float(us[q] & 0xffff0000u), sl, acc[2 * q + 1]) + bb[2 * q + 1], 0.f);
        }
        uint4 o;
        o.x = (unsigned)f2bf(r[0]) | ((unsigned)f2bf(r[1]) << 16);
        o.y = (unsigned)f2bf(r[2]) | ((unsigned)f2bf(r[3]) << 16);
        o.z = (unsigned)f2bf(r[4]) | ((unsigned)f2bf(r[5]) << 16);
        o.w = (unsigned)f2bf(r[6]) | ((unsigned)f2bf(r[7]) << 16);
        ((uint4*)(H + (size_t)n * 128))[fl] = o;
    }
}

// ---- pooling over sorted batch ranges (bf16 input) ----
__global__ __launch_bounds__(128) void k_pool2(const unsigned short* __restrict__ H,
                                               const int* __restrict__ gstart,
                                               float* __restrict__ MX,
                                               float* __restrict__ SM) {
    const int g = blockIdx.x >> 3, slice = blockIdx.x & 7;
    const int f = threadIdx.x;
    const int n0 = gstart[g], n1 = gstart[g + 1];
    float mx = 0.f, sm = 0.f;  // h >= 0 post-relu
    for (int n = n0 + slice; n < n1; n += 8) {
        float v = bf2f(H[(size_t)n * 128 + f]);
        mx = fmaxf(mx, v);
        sm += v;
    }
    atomicMax((unsigned int*)&MX[(size_t)g * 128 + f], __float_as_uint(mx));
    unsafeAtomicAdd(&SM[(size_t)g * 128 + f], sm);
}

// ---- head ----
__global__ __launch_bounds__(64) void k_final(const float* __restrict__ MX,
                                              const float* __restrict__ SM,
                                              const int* __restrict__ gstart,
                                              const float* __restrict__ linW,
                                              const float* __restrict__ linb,
                                              float* __restrict__ out) {
    int g = blockIdx.x, lane = threadIdx.x;
    if (lane < CC) {
        int cnt = gstart[g + 1] - gstart[g];
        float rc = 1.0f / fmaxf((float)cnt, 1.0f);
        float z = linb[lane];
        for (int f = 0; f < 128; f++) {
            z = fmaf(MX[(size_t)g * 128 + f], linW[f * CC + lane], z);
            z = fmaf(SM[(size_t)g * 128 + f] * rc, linW[(128 + f) * CC + lane], z);
        }
        float m = z;
        for (int o = 8; o >= 1; o >>= 1) m = fmaxf(m, __shfl_xor(m, o, 16));
        float ex = expf(z - m), s = ex;
        for (int o = 8; o >= 1; o >>= 1) s += __shfl_xor(s, o, 16);
        out[g * CC + lane] = z - m - logf(s);
    }
}

extern "C" void kernel_launch(void* const* d_in, const int* in_sizes, int n_in,
                              void* d_out, int out_size, void* d_ws, size_t ws_size,
                              hipStream_t stream) {
    const float* x    = (const float*)d_in[0];
    const int*   ei   = (const int*)d_in[1];
    const float* ew   = (const float*)d_in[2];
    const int*   batch= (const int*)d_in[3];
    const float* W1   = (const float*)d_in[4];
    const float* b1   = (const float*)d_in[5];
    const float* W2   = (const float*)d_in[6];
    const float* b2   = (const float*)d_in[7];
    const float* linW = (const float*)d_in[8];
    const float* linb = (const float*)d_in[9];
    float* out = (float*)d_out;

    // workspace layout (8B-aligned blocks first)
    unsigned short* YB = (unsigned short*)d_ws;              // [N,128] bf16 gemm out
    unsigned short* HB = YB + (size_t)NN * 128;              // [N,128] bf16 gather out
    int2*  BUCKET = (int2*)(HB + (size_t)NN * 128);          // [E]
    unsigned long long* DEGC = (unsigned long long*)(BUCKET + EE);  // [N] packed
    float* DINV   = (float*)(DEGC + NN);                     // [N]
    int*   ROWPTR = (int*)(DINV + NN);                       // [N+1]
    int*   RANKE  = ROWPTR + NN + 1;                         // [E]
    int*   GSTART = RANKE + EE;                              // [G+1]
    float* MAXB   = (float*)(GSTART + GG + 1);               // [G,128]  (MAXB+SUMB contiguous)
    float* SUMB   = MAXB + (size_t)GG * 128;                 // [G,128]
    int*   BS     = (int*)(SUMB + (size_t)GG * 128);         // [NBLK]
    int*   BO     = BS + NBLK;                               // [NBLK]
    unsigned short* WT1 = (unsigned short*)(BO + NBLK);      // [128*128]
    unsigned short* WT2 = WT1 + 128 * 128;                   // [128*128]

    const int* src = ei;
    const int* dst = ei + EE;

    // CSR build + W prep
    k_zero<<<NBLK, 256, 0, stream>>>(DEGC, MAXB);
    k_deg<<<(EE + 255) / 256, 256, 0, stream>>>(dst, ew, DEGC, RANKE);
    k_scanA<<<NBLK, 256, 0, stream>>>(DEGC, BS, DINV);
    k_scanB<<<1, 256, 0, stream>>>(BS, BO, batch, GSTART);
    k_scanC<<<NBLK, 256, 0, stream>>>(BO, DEGC, ROWPTR);
    k_binfill<<<1024, 256, 0, stream>>>(src, dst, ew, DINV, ROWPTR, RANKE, BUCKET);
    k_wprep2<<<128, 256, 0, stream>>>(W1, W2, WT1, WT2);

    const int gblk = (NN + 63) / 64;  // 782

    // layer 1
    k_gemm_mfma<1><<<gblk, 256, 0, stream>>>((const void*)x, WT1, YB, NN);
    k_gather<<<(NN + 3) / 4, 256, 0, stream>>>(YB, ROWPTR, BUCKET, DINV, b1, HB);

    // layer 2
    k_gemm_mfma<0><<<gblk, 256, 0, stream>>>((const void*)HB, WT2, YB, NN);
    k_gather<<<(NN + 3) / 4, 256, 0, stream>>>(YB, ROWPTR, BUCKET, DINV, b2, HB);

    // pooling + head
    k_pool2<<<GG * 8, 128, 0, stream>>>(HB, GSTART, MAXB, SUMB);
    k_final<<<GG, 64, 0, stream>>>(MAXB, SUMB, GSTART, linW, linb, out);
}

// Round 8
// 167.496 us; speedup vs baseline: 6.2060x; 1.0434x over previous
//
#include <hip/hip_runtime.h>
#include <hip/hip_bf16.h>

#define NN 50000
#define EE 600000
#define FH 128
#define GG 128
#define CC 16
#define NBLK ((NN + 255) / 256)   // 196 scan blocks
#define GEMMB 782                 // 64-row gemm tiles for N rows

typedef __attribute__((ext_vector_type(8))) short bf16x8;
typedef __attribute__((ext_vector_type(4))) float f32x4;

#define FIXS 1.099511627776e12f   // 2^40
#define FIXI (1.0f / 1.099511627776e12f)

static __device__ __forceinline__ unsigned short f2bf(float f) {
    union { float f; unsigned int u; } v; v.f = f;
    unsigned int r = v.u + 0x7fffu + ((v.u >> 16) & 1u);   // RNE
    return (unsigned short)(r >> 16);
}
static __device__ __forceinline__ float bf2f(unsigned short h) {
    union { unsigned int u; float f; } v; v.u = ((unsigned int)h) << 16;
    return v.f;
}

// ---- prep: zero DEGC | transpose W1,W2 to bf16 | gstart binary search ----
__global__ __launch_bounds__(256) void k_prep(const float* __restrict__ W1,
                                              const float* __restrict__ W2,
                                              unsigned short* __restrict__ WT1,
                                              unsigned short* __restrict__ WT2,
                                              unsigned long long* __restrict__ degc,
                                              const int* __restrict__ batch,
                                              int* __restrict__ gstart) {
    const int b = blockIdx.x, t = threadIdx.x;
    if (b < NBLK) {
        int i = b * 256 + t;
        if (i < NN) degc[i] = 0ULL;
    } else if (b < NBLK + 128) {
        int o = (b - NBLK) * 256 + t;          // 0..32767
        const float* W = (o < 16384) ? W1 : W2;
        unsigned short* WT = (o < 16384) ? WT1 : WT2;
        int oo = o & 16383;
        int c = oo >> 7, k = oo & 127;
        WT[oo] = f2bf(W[k * 128 + c]);
    } else {
        if (t <= GG) {
            int lo = 0, hi = NN;
            while (lo < hi) {
                int mid = (lo + hi) >> 1;
                if (batch[mid] < t) lo = mid + 1; else hi = mid;
            }
            gstart[t] = lo;
        }
    }
}

// ---- fused GEMM + degree kernel ----
// FUSED=1: grid 4*GEMMB; block%4==0 -> gemm tile, else deg edge-block
// (interleaved so atomic-stalled deg waves co-reside with MFMA waves).
// deg: one u64 atomic per edge packs {count:16 | ew*2^40:48}; returned old
// value's hi bits = this edge's rank within its dst bin.
template<int IN_F32, int FUSED>
__global__ __launch_bounds__(256, 3) void k_gemm_deg(const void* __restrict__ Xin,
                                                     const unsigned short* __restrict__ Wt,
                                                     unsigned short* __restrict__ Y,
                                                     int nrows,
                                                     const int* __restrict__ dst,
                                                     const float* __restrict__ ew,
                                                     unsigned long long* __restrict__ degc,
                                                     int* __restrict__ rank) {
    __shared__ char smem[49152];     // [0,32K)=Wl  [32K,48K)=Xl ; epilogue bounce aliases
    int bgemm;
    if (FUSED) {
        const int gq = blockIdx.x >> 2, r = blockIdx.x & 3;
        if (r != 0) {
            const int degblk = 3 * gq + r - 1;
            const int e = degblk * 256 + threadIdx.x;
            if (e < EE) {
                int d = dst[e];
                unsigned long long enc = (1ULL << 48) | (unsigned long long)(ew[e] * FIXS);
                unsigned long long old = atomicAdd(&degc[d], enc);
                rank[e] = (int)(old >> 48);
            }
            return;
        }
        bgemm = gq;
    } else {
        bgemm = blockIdx.x;
    }

    const int tid = threadIdx.x;
    const int r0 = bgemm * 64;

    // stage: W = 2048 16B-chunks, X = 1024 chunks; 12 per thread
#pragma unroll
    for (int j = 0; j < 12; j++) {
        int ci = tid + 256 * j;
        if (ci < 2048) {             // W chunk
            int row = ci >> 4, slot = ci & 15;
            int loff = row * 256 + ((slot * 16) ^ ((row & 7) << 4));
            *(uint4*)(smem + loff) = ((const uint4*)Wt)[ci];
        } else {                     // X chunk
            int xci = ci - 2048;
            int row = xci >> 4, slot = xci & 15;
            int loff = 32768 + row * 256 + ((slot * 16) ^ ((row & 7) << 4));
            int grow = r0 + row;
            uint4 xv;
            if (IN_F32) {
                float4 f0 = make_float4(0.f, 0.f, 0.f, 0.f), f1 = f0;
                if (grow < nrows) {
                    const float4* xp = (const float4*)((const float*)Xin + (size_t)grow * 128 + slot * 8);
                    f0 = xp[0]; f1 = xp[1];
                }
                xv.x = (unsigned)f2bf(f0.x) | ((unsigned)f2bf(f0.y) << 16);
                xv.y = (unsigned)f2bf(f0.z) | ((unsigned)f2bf(f0.w) << 16);
                xv.z = (unsigned)f2bf(f1.x) | ((unsigned)f2bf(f1.y) << 16);
                xv.w = (unsigned)f2bf(f1.z) | ((unsigned)f2bf(f1.w) << 16);
            } else {
                xv = (grow < nrows)
                   ? ((const uint4*)((const unsigned short*)Xin + (size_t)grow * 128))[slot]
                   : make_uint4(0u, 0u, 0u, 0u);
            }
            *(uint4*)(smem + loff) = xv;
        }
    }
    __syncthreads();

    const int lane = tid & 63, w = tid >> 6;
    const int wr = (w >> 1) * 32, wc = (w & 1) * 64;   // 32 rows x 64 cols per wave
    const int lr = lane & 15, lg = lane >> 4;
    f32x4 acc[2][4];
#pragma unroll
    for (int a = 0; a < 2; a++)
#pragma unroll
        for (int c = 0; c < 4; c++) acc[a][c] = (f32x4){0.f, 0.f, 0.f, 0.f};

#pragma unroll
    for (int t = 0; t < 4; t++) {
        const int kb = t * 64 + lg * 16;
        bf16x8 af[2], bf[4];
#pragma unroll
        for (int i = 0; i < 2; i++) {
            int ar = wr + i * 16 + lr;
            af[i] = *(const bf16x8*)(smem + 32768 + ar * 256 + (kb ^ ((ar & 7) << 4)));
        }
#pragma unroll
        for (int i = 0; i < 4; i++) {
            int bc = wc + i * 16 + lr;
            bf[i] = *(const bf16x8*)(smem + bc * 256 + (kb ^ ((bc & 7) << 4)));
        }
#pragma unroll
        for (int fr = 0; fr < 2; fr++)
#pragma unroll
            for (int fc = 0; fc < 4; fc++)
                acc[fr][fc] = __builtin_amdgcn_mfma_f32_16x16x32_bf16(af[fr], bf[fc], acc[fr][fc], 0, 0, 0);
    }

    // epilogue: bounce through LDS (pitch 272B) for coalesced bf16 stores
    __syncthreads();
#pragma unroll
    for (int fr = 0; fr < 2; fr++)
#pragma unroll
        for (int fc = 0; fc < 4; fc++)
#pragma unroll
            for (int j = 0; j < 4; j++) {
                int row = wr + fr * 16 + lg * 4 + j;
                int col = wc + fc * 16 + lr;
                *(unsigned short*)(smem + row * 272 + col * 2) = f2bf(acc[fr][fc][j]);
            }
    __syncthreads();
#pragma unroll
    for (int j = 0; j < 4; j++) {
        int ci = tid + 256 * j;
        int row = ci >> 4, slot = ci & 15;
        int grow = r0 + row;
        if (grow < nrows)
            ((uint4*)(Y + (size_t)grow * 128))[slot] = *(const uint4*)(smem + row * 272 + slot * 16);
    }
}

// ---- scanA: per-block sums of counts; also dinv = rsqrt(deg+1) ----
__global__ __launch_bounds__(256) void k_scanA(const unsigned long long* __restrict__ degc,
                                               int* __restrict__ bs,
                                               float* __restrict__ dinv) {
    int i = blockIdx.x * 256 + threadIdx.x;
    int v = 0;
    if (i < NN) {
        unsigned long long d = degc[i];
        v = (int)(d >> 48);
        float deg = (float)(d & 0xFFFFFFFFFFFFULL) * FIXI;
        dinv[i] = rsqrtf(deg + 1.0f);
    }
#pragma unroll
    for (int o = 32; o >= 1; o >>= 1) v += __shfl_down(v, o, 64);
    __shared__ int ws[4];
    if ((threadIdx.x & 63) == 0) ws[threadIdx.x >> 6] = v;
    __syncthreads();
    if (threadIdx.x == 0) bs[blockIdx.x] = ws[0] + ws[1] + ws[2] + ws[3];
}

// ---- scanBC: each block scans all block-sums in LDS (redundant, cheap),
//      takes its own exclusive offset, then scans its 256-count chunk ----
__global__ __launch_bounds__(256) void k_scanBC(const int* __restrict__ bs,
                                                const unsigned long long* __restrict__ degc,
                                                int* __restrict__ rowptr) {
    __shared__ int sb[256];
    __shared__ int sc[256];
    const int t = threadIdx.x, b = blockIdx.x;
    int vb = (t < NBLK) ? bs[t] : 0;
    sb[t] = vb;
    __syncthreads();
    for (int off = 1; off < 256; off <<= 1) {
        int add = (t >= off) ? sb[t - off] : 0;
        __syncthreads();
        sb[t] += add;
        __syncthreads();
    }
    const int boff = (b > 0) ? sb[b - 1] : 0;
    const int i = b * 256 + t;
    int v = (i < NN) ? (int)(degc[i] >> 48) : 0;
    sc[t] = v;
    __syncthreads();
    for (int off = 1; off < 256; off <<= 1) {
        int add = (t >= off) ? sc[t - off] : 0;
        __syncthreads();
        sc[t] += add;
        __syncthreads();
    }
    int excl = sc[t] - v + boff;
    if (i < NN) rowptr[i] = excl;
    if (i == 0) rowptr[NN] = EE;
}

// ---- fill CSR buckets, no atomics: pos = rowptr[d] + rank[e] ----
__global__ __launch_bounds__(256) void k_binfill(const int* __restrict__ src,
                                                 const int* __restrict__ dst,
                                                 const float* __restrict__ ew,
                                                 const float* __restrict__ dinv,
                                                 const int* __restrict__ rowptr,
                                                 const int* __restrict__ rank,
                                                 int2* __restrict__ bucket) {
    int e = blockIdx.x * 256 + threadIdx.x;
    if (e < EE) {
        int s = src[e], d = dst[e];
        float nm = dinv[s] * ew[e] * dinv[d];
        bucket[rowptr[d] + rank[e]] = make_int2(s, __float_as_int(nm));
    }
}

// ---- gather-aggregate + self-loop + bias + relu (bf16 in/out) ----
// One wave per node; 4 edge-groups x 2-deep unroll = 8 row loads in flight.
__global__ __launch_bounds__(256) void k_gather(const unsigned short* __restrict__ XW,
                                                const int* __restrict__ rowptr,
                                                const int2* __restrict__ bucket,
                                                const float* __restrict__ dinv,
                                                const float* __restrict__ b,
                                                unsigned short* __restrict__ H) {
    const int wv = threadIdx.x >> 6, lane = threadIdx.x & 63;
    const int n = blockIdx.x * 4 + wv;
    if (n >= NN) return;
    const int eg = lane >> 4;        // edge group 0..3
    const int fl = lane & 15;        // 16B feature slot -> features 8*fl..8*fl+7
    const float di = dinv[n];
    const float sl = di * di;
    uint4 su = ((const uint4*)(XW + (size_t)n * 128))[fl];
    float acc[8];
#pragma unroll
    for (int q = 0; q < 8; q++) acc[q] = 0.f;
    const int e0 = rowptr[n], e1 = rowptr[n + 1];
    int e = e0 + eg;
    for (; e + 4 < e1; e += 8) {     // 2 edges per group per iter
        int2 p0 = bucket[e];
        int2 p1 = bucket[e + 4];
        float nm0 = __int_as_float(p0.y);
        float nm1 = __int_as_float(p1.y);
        uint4 v0 = ((const uint4*)(XW + (size_t)p0.x * 128))[fl];
        uint4 v1 = ((const uint4*)(XW + (size_t)p1.x * 128))[fl];
        unsigned int u0[4] = {v0.x, v0.y, v0.z, v0.w};
        unsigned int u1[4] = {v1.x, v1.y, v1.z, v1.w};
#pragma unroll
        for (int q = 0; q < 4; q++) {
            acc[2 * q]     = fmaf(__uint_as_float(u0[q] << 16), nm0, acc[2 * q]);
            acc[2 * q + 1] = fmaf(__uint_as_float(u0[q] & 0xffff0000u), nm0, acc[2 * q + 1]);
            acc[2 * q]     = fmaf(__uint_as_float(u1[q] << 16), nm1, acc[2 * q]);
            acc[2 * q + 1] = fmaf(__uint_as_float(u1[q] & 0xffff0000u), nm1, acc[2 * q + 1]);
        }
    }
    if (e < e1) {                    // tail edge for this group
        int2 p = bucket[e];
        float nm = __int_as_float(p.y);
        uint4 v = ((const uint4*)(XW + (size_t)p.x * 128))[fl];
        unsigned int uu[4] = {v.x, v.y, v.z, v.w};
#pragma unroll
        for (int q = 0; q < 4; q++) {
            acc[2 * q]     = fmaf(__uint_as_float(uu[q] << 16), nm, acc[2 * q]);
            acc[2 * q + 1] = fmaf(__uint_as_float(uu[q] & 0xffff0000u), nm, acc[2 * q + 1]);
        }
    }
#pragma unroll
    for (int q = 0; q < 8; q++) {
        acc[q] += __shfl_xor(acc[q], 16);
        acc[q] += __shfl_xor(acc[q], 32);
    }
    if (eg == 0) {
        unsigned int us[4] = {su.x, su.y, su.z, su.w};
        float4 b0 = ((const float4*)b)[fl * 2];
        float4 b1 = ((const float4*)b)[fl * 2 + 1];
        float bb[8] = {b0.x, b0.y, b0.z, b0.w, b1.x, b1.y, b1.z, b1.w};
        float r[8];
#pragma unroll
        for (int q = 0; q < 4; q++) {
            r[2 * q]     = fmaxf(fmaf(__uint_as_float(us[q] << 16), sl, acc[2 * q]) + bb[2 * q], 0.f);
            r[2 * q + 1] = fmaxf(fmaf(__uint_as_float(us[q] & 0xffff0000u), sl, acc[2 * q + 1]) + bb[2 * q + 1], 0.f);
        }
        uint4 o;
        o.x = (unsigned)f2bf(r[0]) | ((unsigned)f2bf(r[1]) << 16);
        o.y = (unsigned)f2bf(r[2]) | ((unsigned)f2bf(r[3]) << 16);
        o.z = (unsigned)f2bf(r[4]) | ((unsigned)f2bf(r[5]) << 16);
        o.w = (unsigned)f2bf(r[6]) | ((unsigned)f2bf(r[7]) << 16);
        ((uint4*)(H + (size_t)n * 128))[fl] = o;
    }
}

// ---- fused pooling + head: one block per graph, no atomics ----
__global__ __launch_bounds__(256) void k_poolhead(const unsigned short* __restrict__ H,
                                                  const int* __restrict__ gstart,
                                                  const float* __restrict__ linW,
                                                  const float* __restrict__ linb,
                                                  float* __restrict__ out) {
    __shared__ float lmx[512], lsm[512];
    __shared__ float mxf[128], mnf[128];
    const int g = blockIdx.x, t = threadIdx.x;
    const int slice = t >> 6;        // 0..3 node slices
    const int fp = t & 63;           // feature pair -> features 2fp, 2fp+1
    const int n0 = gstart[g], n1 = gstart[g + 1];
    float mx0 = 0.f, mx1 = 0.f, sm0 = 0.f, sm1 = 0.f;   // h >= 0 post-relu
    for (int n = n0 + slice; n < n1; n += 4) {
        unsigned int u = *(const unsigned int*)(H + (size_t)n * 128 + fp * 2);
        float v0 = bf2f((unsigned short)(u & 0xffffu));
        float v1 = bf2f((unsigned short)(u >> 16));
        mx0 = fmaxf(mx0, v0); mx1 = fmaxf(mx1, v1);
        sm0 += v0; sm1 += v1;
    }
    lmx[slice * 128 + fp * 2] = mx0; lmx[slice * 128 + fp * 2 + 1] = mx1;
    lsm[slice * 128 + fp * 2] = sm0; lsm[slice * 128 + fp * 2 + 1] = sm1;
    __syncthreads();
    if (t < 128) {
        float m = fmaxf(fmaxf(lmx[t], lmx[128 + t]), fmaxf(lmx[256 + t], lmx[384 + t]));
        float s = lsm[t] + lsm[128 + t] + lsm[256 + t] + lsm[384 + t];
        mxf[t] = m;
        mnf[t] = s / fmaxf((float)(n1 - n0), 1.0f);
    }
    __syncthreads();
    if (t < CC) {
        float z = linb[t];
        for (int f = 0; f < 128; f++) {
            z = fmaf(mxf[f], linW[f * CC + t], z);
            z = fmaf(mnf[f], linW[(128 + f) * CC + t], z);
        }
        float m = z;
        for (int o = 8; o >= 1; o >>= 1) m = fmaxf(m, __shfl_xor(m, o, 16));
        float ex = expf(z - m), s = ex;
        for (int o = 8; o >= 1; o >>= 1) s += __shfl_xor(s, o, 16);
        out[g * CC + t] = z - m - logf(s);
    }
}

extern "C" void kernel_launch(void* const* d_in, const int* in_sizes, int n_in,
                              void* d_out, int out_size, void* d_ws, size_t ws_size,
                              hipStream_t stream) {
    const float* x    = (const float*)d_in[0];
    const int*   ei   = (const int*)d_in[1];
    const float* ew   = (const float*)d_in[2];
    const int*   batch= (const int*)d_in[3];
    const float* W1   = (const float*)d_in[4];
    const float* b1   = (const float*)d_in[5];
    const float* W2   = (const float*)d_in[6];
    const float* b2   = (const float*)d_in[7];
    const float* linW = (const float*)d_in[8];
    const float* linb = (const float*)d_in[9];
    float* out = (float*)d_out;

    // workspace layout (8B-aligned blocks first)
    unsigned short* YB = (unsigned short*)d_ws;              // [N,128] bf16 gemm out
    unsigned short* HB = YB + (size_t)NN * 128;              // [N,128] bf16 gather out
    int2*  BUCKET = (int2*)(HB + (size_t)NN * 128);          // [E]
    unsigned long long* DEGC = (unsigned long long*)(BUCKET + EE);  // [N] packed
    float* DINV   = (float*)(DEGC + NN);                     // [N]
    int*   ROWPTR = (int*)(DINV + NN);                       // [N+1]
    int*   RANKE  = ROWPTR + NN + 1;                         // [E]
    int*   GSTART = RANKE + EE;                              // [G+1]
    int*   BS     = GSTART + GG + 1;                         // [NBLK]
    unsigned short* WT1 = (unsigned short*)(BS + NBLK);      // [128*128]
    unsigned short* WT2 = WT1 + 128 * 128;                   // [128*128]

    const int* src = ei;
    const int* dst = ei + EE;

    // prep: zero DEGC | W transpose | gstart
    k_prep<<<NBLK + 128 + 1, 256, 0, stream>>>(W1, W2, WT1, WT2, DEGC, batch, GSTART);

    // fused: gemm1 tiles interleaved with deg edge-blocks (atomics hide under MFMA)
    k_gemm_deg<1, 1><<<GEMMB * 4, 256, 0, stream>>>((const void*)x, WT1, YB, NN,
                                                    dst, ew, DEGC, RANKE);

    // CSR build
    k_scanA<<<NBLK, 256, 0, stream>>>(DEGC, BS, DINV);
    k_scanBC<<<NBLK, 256, 0, stream>>>(BS, DEGC, ROWPTR);
    k_binfill<<<(EE + 255) / 256, 256, 0, stream>>>(src, dst, ew, DINV, ROWPTR, RANKE, BUCKET);

    // layer 1 aggregate
    k_gather<<<(NN + 3) / 4, 256, 0, stream>>>(YB, ROWPTR, BUCKET, DINV, b1, HB);

    // layer 2
    k_gemm_deg<0, 0><<<GEMMB, 256, 0, stream>>>((const void*)HB, WT2, YB, NN,
                                                nullptr, nullptr, nullptr, nullptr);
    k_gather<<<(NN + 3) / 4, 256, 0, stream>>>(YB, ROWPTR, BUCKET, DINV, b2, HB);

    // pooling + head (one block per graph)
    k_poolhead<<<GG, 256, 0, stream>>>(HB, GSTART, linW, linb, out);
}